// Round 8
// baseline (192.789 us; speedup 1.0000x reference)
//
#include <hip/hip_runtime.h>
#include <cstdint>

// Shapes (fixed by the problem): B=2, C=64, G=4 -> CG=256, DQK=8, L=64*64=4096
constexpr int Bc  = 2;
constexpr int CGc = 256;
constexpr int Dc  = 8;
constexpr int Lc  = 4096;

typedef __attribute__((ext_vector_type(8))) short short8;
typedef __attribute__((ext_vector_type(4))) float floatx4;

__device__ inline unsigned short f2bf(float f) {
  union { float f; unsigned u; } v; v.f = f;
  unsigned r = v.u + 0x7fffu + ((v.u >> 16) & 1u);
  return (unsigned short)(r >> 16);
}
__device__ inline float bf2f(unsigned short h) {
  return __uint_as_float((unsigned)h << 16);
}

// ---------------------------------------------------------------------------
// Phase 0: Wcat[cc][k] bf16 = [[Wr, -Wi], [Wi, Wr]] (512x512) for v_gemm.
// ---------------------------------------------------------------------------
__global__ __launch_bounds__(256) void wcat_pack(const float* __restrict__ wv,
                                                 unsigned short* __restrict__ Wcat) {
  const int i  = blockIdx.x * 256 + threadIdx.x;  // 0..262143
  const int cc = i >> 9, k = i & 511;
  const int co = cc >> 8, c = cc & 255, ci = k >> 8, cin = k & 255;
  const float wr = wv[(size_t)c * CGc + cin];
  const float wi = wv[(size_t)(CGc + c) * CGc + cin];
  const float val = co == 0 ? (ci == 0 ? wr : -wi) : (ci == 0 ? wi : wr);
  Wcat[i] = f2bf(val);
}

// ---------------------------------------------------------------------------
// Phase 0b: LDS-transpose x -> Xlk[b][l][cin2] bf16 (cin2 = comp*256+cin).
// ---------------------------------------------------------------------------
__global__ __launch_bounds__(256) void xT_pack(const float* __restrict__ x,
                                               unsigned short* __restrict__ Xlk) {
  __shared__ float xs[64][65];
  const int tid = threadIdx.x;
  const int b   = blockIdx.z;
  const int l0  = blockIdx.x * 64;
  const int c0  = blockIdx.y * 64;
  const int lt  = tid & 63, r4 = tid >> 6;
#pragma unroll
  for (int p = 0; p < 16; ++p) {
    const int row  = p * 4 + r4;
    const int cin2 = c0 + row;
    const int comp = cin2 >> 8, cin = cin2 & 255;
    xs[row][lt] = x[((size_t)(comp * Bc + b) * CGc + cin) * Lc + l0 + lt];
  }
  __syncthreads();
#pragma unroll
  for (int p = 0; p < 16; ++p) {
    const int lr = p * 4 + r4;
    Xlk[((size_t)b * Lc + l0 + lr) * 512 + c0 + lt] = f2bf(xs[lt][lr]);
  }
}

// ---------------------------------------------------------------------------
// Phase 1 (fused): complex Q AND K projections + split-bf16 MFMA packing in
// one kernel (verified round-6 structure, unchanged).
// ---------------------------------------------------------------------------
__global__ __launch_bounds__(256) void qk_projpack(const float* __restrict__ x,
                                                   const float* __restrict__ wq,
                                                   const float* __restrict__ wk,
                                                   unsigned short* __restrict__ Qcat,
                                                   unsigned short* __restrict__ K1hi,
                                                   unsigned short* __restrict__ K1lo,
                                                   unsigned short* __restrict__ K2hi,
                                                   unsigned short* __restrict__ K2lo) {
  __shared__ float ws[4 * Dc * CGc];  // 32 KB: wq_r | wq_i | wk_r | wk_i
  __shared__ float qs[32][16];        // 2 KB: q~ rows
  __shared__ float ks[32][16];        // 2 KB: k~ rows
  const int tid = threadIdx.x;
  const int b   = blockIdx.y;
  for (int i = tid; i < 2 * Dc * CGc; i += 256) {
    ws[i]                 = wq[i];
    ws[2 * Dc * CGc + i]  = wk[i];
  }
  __syncthreads();
  const int d  = tid >> 5;   // 0..7
  const int ml = tid & 31;   // 0..31
  const int m  = blockIdx.x * 32 + ml;
  const float* xr = x + ((size_t)(0 * Bc + b) * CGc) * Lc + m;
  const float* xi = x + ((size_t)(1 * Bc + b) * CGc) * Lc + m;
  const float* wqr = ws + d * CGc;
  const float* wqi = ws + (Dc + d) * CGc;
  const float* wkr = ws + 2 * Dc * CGc + d * CGc;
  const float* wki = ws + 2 * Dc * CGc + (Dc + d) * CGc;
  float qer = 0.f, qei = 0.f, ker = 0.f, kei = 0.f;
#pragma unroll 4
  for (int cin = 0; cin < CGc; ++cin) {
    const float vr = xr[(size_t)cin * Lc];
    const float vi = xi[(size_t)cin * Lc];
    const float a1 = wqr[cin], b1 = wqi[cin];
    qer = fmaf(a1, vr, qer); qer = fmaf(-b1, vi, qer);
    qei = fmaf(a1, vi, qei); qei = fmaf(b1, vr, qei);
    const float a2 = wkr[cin], b2 = wki[cin];
    ker = fmaf(a2, vr, ker); ker = fmaf(-b2, vi, ker);
    kei = fmaf(a2, vi, kei); kei = fmaf(b2, vr, kei);
  }
  qs[ml][d] = qer;  qs[ml][8 + d] = qei;
  ks[ml][d] = ker;  ks[ml][8 + d] = kei;
  __syncthreads();
  // --- pack stage ---
  const int part = tid >> 5;       // 0..7
  const int rl   = tid & 31;       // local row
  const size_t r = (size_t)b * Lc + blockIdx.x * 32 + rl;
  if (part < 2) {
    unsigned u[8];
#pragma unroll
    for (int t = 0; t < 8; ++t) {
      const float v0 = qs[rl][2 * t], v1 = qs[rl][2 * t + 1];
      const unsigned short h0 = f2bf(v0), h1 = f2bf(v1);
      if (part == 0) {
        u[t] = (unsigned)h0 | ((unsigned)h1 << 16);
      } else {
        const unsigned short l0 = f2bf(v0 - bf2f(h0));
        const unsigned short l1 = f2bf(v1 - bf2f(h1));
        u[t] = (unsigned)l0 | ((unsigned)l1 << 16);
      }
    }
    uint4* dst = (uint4*)(Qcat + r * 32 + part * 16);
    dst[0] = make_uint4(u[0], u[1], u[2], u[3]);
    dst[1] = make_uint4(u[4], u[5], u[6], u[7]);
  } else if (part < 6) {
    float kv[16];
    if (part < 4) {
#pragma unroll
      for (int e = 0; e < 8; ++e) { kv[e] = ks[rl][e]; kv[8 + e] = -ks[rl][8 + e]; }
    } else {
#pragma unroll
      for (int e = 0; e < 8; ++e) { kv[e] = ks[rl][8 + e]; kv[8 + e] = ks[rl][e]; }
    }
    const int lo = part & 1;
    unsigned u[8];
#pragma unroll
    for (int t = 0; t < 8; ++t) {
      const unsigned short h0 = f2bf(kv[2 * t]), h1 = f2bf(kv[2 * t + 1]);
      if (!lo) {
        u[t] = (unsigned)h0 | ((unsigned)h1 << 16);
      } else {
        const unsigned short l0 = f2bf(kv[2 * t] - bf2f(h0));
        const unsigned short l1 = f2bf(kv[2 * t + 1] - bf2f(h1));
        u[t] = (unsigned)l0 | ((unsigned)l1 << 16);
      }
    }
    unsigned short* base = part < 4 ? (lo ? K1lo : K1hi) : (lo ? K2lo : K2hi);
    uint4* dst = (uint4*)(base + r * 16);
    dst[0] = make_uint4(u[0], u[1], u[2], u[3]);
    dst[1] = make_uint4(u[4], u[5], u[6], u[7]);
  }
}

// ---------------------------------------------------------------------------
// Phase 2: V projection as bf16 MFMA GEMM (unchanged, verified).
// ---------------------------------------------------------------------------
__global__ __launch_bounds__(256) void v_gemm(const unsigned short* __restrict__ Wcat,
                                              const unsigned short* __restrict__ Xlk,
                                              unsigned short* __restrict__ vbf) {
  __shared__ short As[128 * 64];
  __shared__ short Bs[64 * 64];
  const int tid  = threadIdx.x;
  const int b    = blockIdx.z;
  const int cc0  = blockIdx.x * 128;
  const int l0   = blockIdx.y * 64;
  const int wid  = tid >> 6, lane = tid & 63;
  const int wcc  = (wid >> 1) * 64;
  const int wl   = (wid & 1) * 32;
  const int lrow = lane & 15, quad = lane >> 4;
  floatx4 acc[4][2] = {};
  const unsigned short* wsrc = Wcat + (size_t)cc0 * 512;
  const unsigned short* xsrc = Xlk + ((size_t)b * Lc + l0) * 512;
  int s_off[4], g_off[4];
#pragma unroll
  for (int r = 0; r < 4; ++r) {
    const int idx = r * 256 + tid;
    const int row = idx >> 3, ch = idx & 7;
    s_off[r] = row * 64 + (ch ^ (row & 7)) * 8;
    g_off[r] = row * 512 + ch * 8;
  }
  short8 ar[4], br[2];
#pragma unroll
  for (int r = 0; r < 4; ++r) ar[r] = *(const short8*)(wsrc + g_off[r]);
#pragma unroll
  for (int r = 0; r < 2; ++r) br[r] = *(const short8*)(xsrc + g_off[r]);
  for (int k0 = 0; k0 < 512; k0 += 64) {
    __syncthreads();
#pragma unroll
    for (int r = 0; r < 4; ++r) *(short8*)&As[s_off[r]] = ar[r];
#pragma unroll
    for (int r = 0; r < 2; ++r) *(short8*)&Bs[s_off[r]] = br[r];
    __syncthreads();
    if (k0 + 64 < 512) {
#pragma unroll
      for (int r = 0; r < 4; ++r) ar[r] = *(const short8*)(wsrc + g_off[r] + k0 + 64);
#pragma unroll
      for (int r = 0; r < 2; ++r) br[r] = *(const short8*)(xsrc + g_off[r] + k0 + 64);
    }
#pragma unroll
    for (int kk = 0; kk < 64; kk += 32) {
      const int cb = kk >> 3;  // 0 or 4
      short8 af[4], bf[2];
#pragma unroll
      for (int i = 0; i < 4; ++i)
        af[i] = *(const short8*)&As[(wcc + i * 16 + lrow) * 64 +
                                    ((cb + quad) ^ (lrow & 7)) * 8];
#pragma unroll
      for (int j = 0; j < 2; ++j)
        bf[j] = *(const short8*)&Bs[(wl + j * 16 + lrow) * 64 +
                                    ((cb + quad) ^ (lrow & 7)) * 8];
#pragma unroll
      for (int i = 0; i < 4; ++i)
#pragma unroll
        for (int j = 0; j < 2; ++j)
          acc[i][j] = __builtin_amdgcn_mfma_f32_16x16x32_bf16(af[i], bf[j], acc[i][j], 0, 0, 0);
    }
  }
#pragma unroll
  for (int i = 0; i < 4; ++i) {
    const int ccb = cc0 + wcc + i * 16 + quad * 4;
#pragma unroll
    for (int j = 0; j < 2; ++j) {
      const int l = l0 + wl + j * 16 + lrow;
#pragma unroll
      for (int rg = 0; rg < 4; ++rg)
        vbf[((size_t)b * 512 + ccb + rg) * Lc + l] = f2bf(acc[i][j][rg]);
    }
  }
}

// ---------------------------------------------------------------------------
// Phase 3+4 fused: emax_exp v2 — 4x l-unroll with batched load staging.
// Same math/stores as the verified round-7 kernel; only load scheduling
// changes: per group, all 8 (pass 1) / 16 (pass 2) independent short8
// loads issue into register arrays BEFORE any consuming MFMA -> 4x MLP
// (round-7 profile: VGPR=28, 440 cyc/iter = un-pipelined L2 latency).
// 1024 threads = 16 waves: 2 row-groups x 8 l-slices of 512.
// ---------------------------------------------------------------------------
__global__ __launch_bounds__(1024, 4) void emax_exp(const unsigned short* __restrict__ Qcat,
                                                    const unsigned short* __restrict__ K1hi,
                                                    const unsigned short* __restrict__ K1lo,
                                                    const unsigned short* __restrict__ K2hi,
                                                    const unsigned short* __restrict__ K2lo,
                                                    unsigned short* __restrict__ att,
                                                    float* __restrict__ Ssum) {
  __shared__ unsigned maxb[32];
  __shared__ float    sumb[32];
  const int tid  = threadIdx.x;
  const int wv   = tid >> 6, lane = tid & 63;
  const int lrow = lane & 15, quad = lane >> 4, qsel = quad & 1;
  const int b    = blockIdx.y;
  const int rg   = wv & 1;            // row-group (16 rows each)
  const int sl   = wv >> 1;           // l-slice 0..7
  const int m16  = blockIdx.x * 32 + rg * 16;
  const int lbeg = sl * 512;
  const size_t kb = (size_t)b * Lc;
  if (tid < 32) { maxb[tid] = 0u; sumb[tid] = 0.f; }
  __syncthreads();
  const short8 afrag = *(const short8*)(Qcat + (kb + m16 + lrow) * 32 + quad * 8);
  // ---- pass 1: hi-only row max, 4x unrolled (8 loads in flight) ----
  float mx[4] = {0.f, 0.f, 0.f, 0.f};
  for (int l0 = lbeg; l0 < lbeg + 512; l0 += 64) {
    short8 b1h[4], b2h[4];
#pragma unroll
    for (int u = 0; u < 4; ++u) {
      const size_t l = kb + l0 + u * 16 + lrow;
      b1h[u] = *(const short8*)(K1hi + l * 16 + qsel * 8);
      b2h[u] = *(const short8*)(K2hi + l * 16 + qsel * 8);
    }
#pragma unroll
    for (int u = 0; u < 4; ++u) {
      const floatx4 er = __builtin_amdgcn_mfma_f32_16x16x32_bf16(afrag, b1h[u], (floatx4){0.f, 0.f, 0.f, 0.f}, 0, 0, 0);
      const floatx4 ei = __builtin_amdgcn_mfma_f32_16x16x32_bf16(afrag, b2h[u], (floatx4){0.f, 0.f, 0.f, 0.f}, 0, 0, 0);
#pragma unroll
      for (int r = 0; r < 4; ++r) {
        float e = er[r] * er[r];
        e = fmaf(ei[r], ei[r], e);
        mx[r] = fmaxf(mx[r], e);
      }
    }
  }
#pragma unroll
  for (int r = 0; r < 4; ++r) {
    float v = mx[r];
#pragma unroll
    for (int off = 1; off < 16; off <<= 1) v = fmaxf(v, __shfl_xor(v, off));
    if (lrow == 0)
      atomicMax(&maxb[rg * 16 + quad * 4 + r], __float_as_uint(v));  // E >= 0
  }
  __syncthreads();
  float Mv[4], sum[4] = {};
#pragma unroll
  for (int r = 0; r < 4; ++r) Mv[r] = __uint_as_float(maxb[rg * 16 + quad * 4 + r]);
  // ---- pass 2: refined E, exp, att store, 4x unrolled (16 loads in flight) ----
  for (int l0 = lbeg; l0 < lbeg + 512; l0 += 64) {
    short8 b1h[4], b1l[4], b2h[4], b2l[4];
#pragma unroll
    for (int u = 0; u < 4; ++u) {
      const size_t l = kb + l0 + u * 16 + lrow;
      b1h[u] = *(const short8*)(K1hi + l * 16 + qsel * 8);
      b1l[u] = *(const short8*)(K1lo + l * 16 + qsel * 8);
      b2h[u] = *(const short8*)(K2hi + l * 16 + qsel * 8);
      b2l[u] = *(const short8*)(K2lo + l * 16 + qsel * 8);
    }
#pragma unroll
    for (int u = 0; u < 4; ++u) {
      floatx4 er = __builtin_amdgcn_mfma_f32_16x16x32_bf16(afrag, b1l[u], (floatx4){0.f, 0.f, 0.f, 0.f}, 0, 0, 0);
      er = __builtin_amdgcn_mfma_f32_16x16x32_bf16(afrag, b1h[u], er, 0, 0, 0);
      floatx4 ei = __builtin_amdgcn_mfma_f32_16x16x32_bf16(afrag, b2l[u], (floatx4){0.f, 0.f, 0.f, 0.f}, 0, 0, 0);
      ei = __builtin_amdgcn_mfma_f32_16x16x32_bf16(afrag, b2h[u], ei, 0, 0, 0);
#pragma unroll
      for (int r = 0; r < 4; ++r) {
        float e = er[r] * er[r];
        e = fmaf(ei[r], ei[r], e);
        const float wgt = __expf(e - Mv[r]);
        sum[r] += wgt;
        att[(kb + m16 + quad * 4 + r) * Lc + l0 + u * 16 + lrow] = f2bf(wgt);
      }
    }
  }
#pragma unroll
  for (int r = 0; r < 4; ++r) {
    float v = sum[r];
#pragma unroll
    for (int off = 1; off < 16; off <<= 1) v += __shfl_xor(v, off);
    if (lrow == 0) atomicAdd(&sumb[rg * 16 + quad * 4 + r], v);
  }
  __syncthreads();
  if (tid < 32) Ssum[kb + blockIdx.x * 32 + tid] = sumb[tid];
}

// ---------------------------------------------------------------------------
// Phase 5: PV GEMM v3 (unchanged, verified round-7): 1024 threads, 4-way
// split-K, K=128 tiles, 2 x 64 KB DMA buffers, one barrier per phase.
// ---------------------------------------------------------------------------
__device__ __forceinline__ void pv_stage128(const unsigned short* __restrict__ vsrc,
                                            const unsigned short* __restrict__ asrc,
                                            short* lds_buf, int k0, int wid, int lane) {
  const int rsub = lane >> 4;          // 0..3: row within 4-row block
  const int cs   = lane & 15;          // LDS chunk position within 256B row
#pragma unroll
  for (int t = 0; t < 4; ++t) {
    const int q    = wid * 4 + t;      // block id 0..63 (1 KB each)
    const int tile = q >> 5;           // 0 = A(v), 1 = B(att)
    const int j    = q & 31;           // 4-row group within tile
    const int row  = j * 4 + rsub;
    const int gch  = cs ^ (row & 7);   // inverse-swizzled global k-chunk
    const unsigned short* g =
        (tile == 0 ? vsrc : asrc) + (size_t)row * Lc + k0 + gch * 8;
    short* l = lds_buf + tile * 16384 + j * 512;  // wave-uniform dest base
    __builtin_amdgcn_global_load_lds(
        (const __attribute__((address_space(1))) void*)g,
        (__attribute__((address_space(3))) void*)l, 16, 0, 0);
  }
}

__device__ __forceinline__ void pv_compute128(const short* __restrict__ As,
                                              const short* __restrict__ Bs,
                                              int cb, int wcc, int wm, int lrow, int quad,
                                              floatx4 (&acc)[4][4]) {
  short8 af[4], bf[4];
#pragma unroll
  for (int i = 0; i < 4; ++i)
    af[i] = *(const short8*)&As[(wcc + i * 16 + lrow) * 128 +
                                ((cb + quad) ^ (lrow & 7)) * 8];
#pragma unroll
  for (int j = 0; j < 4; ++j)
    bf[j] = *(const short8*)&Bs[(wm + j * 16 + lrow) * 128 +
                                ((cb + quad) ^ (lrow & 7)) * 8];
#pragma unroll
  for (int i = 0; i < 4; ++i)
#pragma unroll
    for (int j = 0; j < 4; ++j)
      acc[i][j] = __builtin_amdgcn_mfma_f32_16x16x32_bf16(af[i], bf[j], acc[i][j], 0, 0, 0);
}

__global__ __launch_bounds__(1024, 1) void pv_gemm(const unsigned short* __restrict__ v,
                                                   const unsigned short* __restrict__ att,
                                                   const float* __restrict__ Ssum,
                                                   const float* __restrict__ x,
                                                   const float* __restrict__ gamma,
                                                   float* __restrict__ out) {
  // 128 KB dynamic: 2 buffers x {A 128x128 | B 128x128} bf16, XOR-swizzled.
  extern __shared__ short smem[];
  // XCD-aware bijective swizzle: 256 blocks, XCD k gets contiguous work ids.
  const int flat = blockIdx.x;
  const int swz  = (flat & 7) * 32 + (flat >> 3);
  const int b    = swz >> 7;
  const int rem  = swz & 127;
  const int m0   = (rem >> 2) * 128;   // 32 m-panels
  const int cc0  = (rem & 3) * 128;    // 4 cc-panels
  const int tid  = threadIdx.x;
  const int wid  = tid >> 6, lane = tid & 63;
  const int g    = wid >> 2;           // split-K group 0..3
  const int w4   = wid & 3;
  const int wcc  = (w4 >> 1) * 64;
  const int wm   = (w4 & 1) * 64;
  const int lrow = lane & 15, quad = lane >> 4;
  const int cb   = g * 4;              // k-chunk base (of 16 chunks)
  floatx4 acc[4][4] = {};
  const unsigned short* vsrc = v   + ((size_t)b * 512 + cc0) * Lc;
  const unsigned short* asrc = att + ((size_t)b * Lc + m0) * Lc;
  // Prologue: DMA tile 0 into buf0.
  pv_stage128(vsrc, asrc, smem, 0, wid, lane);
  for (int p = 0; p < 32; ++p) {
    asm volatile("s_waitcnt vmcnt(0)" ::: "memory");
    __builtin_amdgcn_s_barrier();       // tile p complete; p-1 compute done
    __builtin_amdgcn_sched_barrier(0);
    if (p + 1 < 32)
      pv_stage128(vsrc, asrc, smem + ((p + 1) & 1) * 32768, (p + 1) * 128, wid, lane);
    __builtin_amdgcn_sched_barrier(0);
    pv_compute128(smem + (p & 1) * 32768, smem + (p & 1) * 32768 + 16384,
                  cb, wcc, wm, lrow, quad, acc);
    __builtin_amdgcn_sched_barrier(0);
  }
  __syncthreads();  // all computes done before smem reuse for reduction
  float* red = (float*)smem;  // 32768 floats = 128 KB
  // Round 1: g1 -> red[0..16383], g3 -> red[16384..32767]
  if (g == 1 || g == 3) {
    float* dst = red + (g == 3 ? 16384 : 0);
#pragma unroll
    for (int i = 0; i < 4; ++i)
#pragma unroll
      for (int j = 0; j < 4; ++j) {
        const int tq = i * 4 + j;
        *(floatx4*)&dst[((w4 * 64 + lane) * 16 + (tq ^ (lane & 15))) * 4] = acc[i][j];
      }
  }
  __syncthreads();
  if (g == 0 || g == 2) {
    const float* src = red + (g == 2 ? 16384 : 0);
#pragma unroll
    for (int i = 0; i < 4; ++i)
#pragma unroll
      for (int j = 0; j < 4; ++j) {
        const int tq = i * 4 + j;
        const floatx4 o = *(const floatx4*)&src[((w4 * 64 + lane) * 16 + (tq ^ (lane & 15))) * 4];
        acc[i][j] += o;
      }
  }
  __syncthreads();
  // Round 2: g2 -> red[0..16383]
  if (g == 2) {
#pragma unroll
    for (int i = 0; i < 4; ++i)
#pragma unroll
      for (int j = 0; j < 4; ++j) {
        const int tq = i * 4 + j;
        *(floatx4*)&red[((w4 * 64 + lane) * 16 + (tq ^ (lane & 15))) * 4] = acc[i][j];
      }
  }
  __syncthreads();
  if (g == 0) {
#pragma unroll
    for (int i = 0; i < 4; ++i)
#pragma unroll
      for (int j = 0; j < 4; ++j) {
        const int tq = i * 4 + j;
        const floatx4 o = *(const floatx4*)&red[((w4 * 64 + lane) * 16 + (tq ^ (lane & 15))) * 4];
        acc[i][j] += o;
      }
    const float gm = gamma[0];
    float svj[4];
#pragma unroll
    for (int j = 0; j < 4; ++j)
      svj[j] = gm / Ssum[(size_t)b * Lc + m0 + wm + j * 16 + lrow];
#pragma unroll
    for (int i = 0; i < 4; ++i) {
      const int ccb = cc0 + wcc + i * 16 + quad * 4;
#pragma unroll
      for (int j = 0; j < 4; ++j) {
        const int m = m0 + wm + j * 16 + lrow;
#pragma unroll
        for (int rg = 0; rg < 4; ++rg) {
          const int cc   = ccb + rg;
          const int comp = cc >> 8, c = cc & 255;
          const size_t idx = (((size_t)comp * Bc + b) * CGc + c) * Lc + m;
          out[idx] = svj[j] * acc[i][j][rg] + x[idx];
        }
      }
    }
  }
}

// ---------------------------------------------------------------------------
extern "C" void kernel_launch(void* const* d_in, const int* in_sizes, int n_in,
                              void* d_out, int out_size, void* d_ws, size_t ws_size,
                              hipStream_t stream) {
  const float* x     = (const float*)d_in[0];
  const float* wq    = (const float*)d_in[1];
  const float* wk    = (const float*)d_in[2];
  const float* wv    = (const float*)d_in[3];
  const float* gamma = (const float*)d_in[4];
  float* out = (float*)d_out;

  // Workspace (~78.7 MB). Xlk aliases att (stream-ordered: v_gemm reads Xlk
  // before emax_exp overwrites the region with att). q/kk/Mrow slots
  // retained for layout stability (unused). Ssum needs no init (direct
  // store from emax_exp).
  float* q    = (float*)d_ws;                         // 131072 (unused)
  float* kk   = q    + (size_t)Bc * Lc * 16;          // 131072 (unused)
  float* Mrow = kk   + (size_t)Bc * Lc * 16;          // 8192 (unused)
  float* Ssum = Mrow + (size_t)Bc * Lc;               // 8192
  unsigned short* vbf  = (unsigned short*)(Ssum + (size_t)Bc * Lc);  // 2*512*4096
  unsigned short* att  = vbf + (size_t)Bc * 512 * Lc;                // 2*4096*4096
  unsigned short* Xlk  = att;                                        // alias (8.4MB)
  unsigned short* Qcat = att + (size_t)Bc * Lc * Lc;                 // 8192*32
  unsigned short* K1hi = Qcat + (size_t)Bc * Lc * 32;                // 8192*16
  unsigned short* K1lo = K1hi + (size_t)Bc * Lc * 16;
  unsigned short* K2hi = K1lo + (size_t)Bc * Lc * 16;
  unsigned short* K2lo = K2hi + (size_t)Bc * Lc * 16;
  unsigned short* Wcat = K2lo + (size_t)Bc * Lc * 16;                // 512*512

  wcat_pack<<<dim3((512 * 512) / 256), 256, 0, stream>>>(wv, Wcat);
  qk_projpack<<<dim3(Lc / 32, Bc), 256, 0, stream>>>(x, wq, wk, Qcat, K1hi, K1lo, K2hi, K2lo);
  xT_pack<<<dim3(Lc / 64, 8, Bc), 256, 0, stream>>>(x, Xlk);
  v_gemm<<<dim3(512 / 128, Lc / 64, Bc), 256, 0, stream>>>(Wcat, Xlk, vbf);
  emax_exp<<<dim3(Lc / 32, Bc), 1024, 0, stream>>>(Qcat, K1hi, K1lo, K2hi, K2lo, att, Ssum);
  pv_gemm<<<dim3(256), 1024, 2 * 32768 * sizeof(short), stream>>>(vbf, att, Ssum, x, gamma, out);
}

// Round 9
// 185.750 us; speedup vs baseline: 1.0379x; 1.0379x over previous
//
#include <hip/hip_runtime.h>
#include <cstdint>

// Shapes (fixed by the problem): B=2, C=64, G=4 -> CG=256, DQK=8, L=64*64=4096
constexpr int Bc  = 2;
constexpr int CGc = 256;
constexpr int Dc  = 8;
constexpr int Lc  = 4096;

typedef __attribute__((ext_vector_type(8))) short short8;
typedef __attribute__((ext_vector_type(4))) float floatx4;

__device__ inline unsigned short f2bf(float f) {
  union { float f; unsigned u; } v; v.f = f;
  unsigned r = v.u + 0x7fffu + ((v.u >> 16) & 1u);
  return (unsigned short)(r >> 16);
}
__device__ inline float bf2f(unsigned short h) {
  return __uint_as_float((unsigned)h << 16);
}

// ---------------------------------------------------------------------------
// Phase 0: Wcat[cc][k] bf16 = [[Wr, -Wi], [Wi, Wr]] (512x512) for v_gemm.
// ---------------------------------------------------------------------------
__global__ __launch_bounds__(256) void wcat_pack(const float* __restrict__ wv,
                                                 unsigned short* __restrict__ Wcat) {
  const int i  = blockIdx.x * 256 + threadIdx.x;  // 0..262143
  const int cc = i >> 9, k = i & 511;
  const int co = cc >> 8, c = cc & 255, ci = k >> 8, cin = k & 255;
  const float wr = wv[(size_t)c * CGc + cin];
  const float wi = wv[(size_t)(CGc + c) * CGc + cin];
  const float val = co == 0 ? (ci == 0 ? wr : -wi) : (ci == 0 ? wi : wr);
  Wcat[i] = f2bf(val);
}

// ---------------------------------------------------------------------------
// Phase 0b: LDS-transpose x -> Xlk[b][l][cin2] bf16 (cin2 = comp*256+cin).
// ---------------------------------------------------------------------------
__global__ __launch_bounds__(256) void xT_pack(const float* __restrict__ x,
                                               unsigned short* __restrict__ Xlk) {
  __shared__ float xs[64][65];
  const int tid = threadIdx.x;
  const int b   = blockIdx.z;
  const int l0  = blockIdx.x * 64;
  const int c0  = blockIdx.y * 64;
  const int lt  = tid & 63, r4 = tid >> 6;
#pragma unroll
  for (int p = 0; p < 16; ++p) {
    const int row  = p * 4 + r4;
    const int cin2 = c0 + row;
    const int comp = cin2 >> 8, cin = cin2 & 255;
    xs[row][lt] = x[((size_t)(comp * Bc + b) * CGc + cin) * Lc + l0 + lt];
  }
  __syncthreads();
#pragma unroll
  for (int p = 0; p < 16; ++p) {
    const int lr = p * 4 + r4;
    Xlk[((size_t)b * Lc + l0 + lr) * 512 + c0 + lt] = f2bf(xs[lt][lr]);
  }
}

// ---------------------------------------------------------------------------
// Phase 1 (fused): complex Q AND K projections + split-bf16 MFMA packing in
// one kernel (verified round-6 structure, unchanged).
// ---------------------------------------------------------------------------
__global__ __launch_bounds__(256) void qk_projpack(const float* __restrict__ x,
                                                   const float* __restrict__ wq,
                                                   const float* __restrict__ wk,
                                                   unsigned short* __restrict__ Qcat,
                                                   unsigned short* __restrict__ K1hi,
                                                   unsigned short* __restrict__ K1lo,
                                                   unsigned short* __restrict__ K2hi,
                                                   unsigned short* __restrict__ K2lo) {
  __shared__ float ws[4 * Dc * CGc];  // 32 KB: wq_r | wq_i | wk_r | wk_i
  __shared__ float qs[32][16];        // 2 KB: q~ rows
  __shared__ float ks[32][16];        // 2 KB: k~ rows
  const int tid = threadIdx.x;
  const int b   = blockIdx.y;
  for (int i = tid; i < 2 * Dc * CGc; i += 256) {
    ws[i]                 = wq[i];
    ws[2 * Dc * CGc + i]  = wk[i];
  }
  __syncthreads();
  const int d  = tid >> 5;   // 0..7
  const int ml = tid & 31;   // 0..31
  const int m  = blockIdx.x * 32 + ml;
  const float* xr = x + ((size_t)(0 * Bc + b) * CGc) * Lc + m;
  const float* xi = x + ((size_t)(1 * Bc + b) * CGc) * Lc + m;
  const float* wqr = ws + d * CGc;
  const float* wqi = ws + (Dc + d) * CGc;
  const float* wkr = ws + 2 * Dc * CGc + d * CGc;
  const float* wki = ws + 2 * Dc * CGc + (Dc + d) * CGc;
  float qer = 0.f, qei = 0.f, ker = 0.f, kei = 0.f;
#pragma unroll 4
  for (int cin = 0; cin < CGc; ++cin) {
    const float vr = xr[(size_t)cin * Lc];
    const float vi = xi[(size_t)cin * Lc];
    const float a1 = wqr[cin], b1 = wqi[cin];
    qer = fmaf(a1, vr, qer); qer = fmaf(-b1, vi, qer);
    qei = fmaf(a1, vi, qei); qei = fmaf(b1, vr, qei);
    const float a2 = wkr[cin], b2 = wki[cin];
    ker = fmaf(a2, vr, ker); ker = fmaf(-b2, vi, ker);
    kei = fmaf(a2, vi, kei); kei = fmaf(b2, vr, kei);
  }
  qs[ml][d] = qer;  qs[ml][8 + d] = qei;
  ks[ml][d] = ker;  ks[ml][8 + d] = kei;
  __syncthreads();
  // --- pack stage ---
  const int part = tid >> 5;       // 0..7
  const int rl   = tid & 31;       // local row
  const size_t r = (size_t)b * Lc + blockIdx.x * 32 + rl;
  if (part < 2) {
    unsigned u[8];
#pragma unroll
    for (int t = 0; t < 8; ++t) {
      const float v0 = qs[rl][2 * t], v1 = qs[rl][2 * t + 1];
      const unsigned short h0 = f2bf(v0), h1 = f2bf(v1);
      if (part == 0) {
        u[t] = (unsigned)h0 | ((unsigned)h1 << 16);
      } else {
        const unsigned short l0 = f2bf(v0 - bf2f(h0));
        const unsigned short l1 = f2bf(v1 - bf2f(h1));
        u[t] = (unsigned)l0 | ((unsigned)l1 << 16);
      }
    }
    uint4* dst = (uint4*)(Qcat + r * 32 + part * 16);
    dst[0] = make_uint4(u[0], u[1], u[2], u[3]);
    dst[1] = make_uint4(u[4], u[5], u[6], u[7]);
  } else if (part < 6) {
    float kv[16];
    if (part < 4) {
#pragma unroll
      for (int e = 0; e < 8; ++e) { kv[e] = ks[rl][e]; kv[8 + e] = -ks[rl][8 + e]; }
    } else {
#pragma unroll
      for (int e = 0; e < 8; ++e) { kv[e] = ks[rl][8 + e]; kv[8 + e] = ks[rl][e]; }
    }
    const int lo = part & 1;
    unsigned u[8];
#pragma unroll
    for (int t = 0; t < 8; ++t) {
      const unsigned short h0 = f2bf(kv[2 * t]), h1 = f2bf(kv[2 * t + 1]);
      if (!lo) {
        u[t] = (unsigned)h0 | ((unsigned)h1 << 16);
      } else {
        const unsigned short l0 = f2bf(kv[2 * t] - bf2f(h0));
        const unsigned short l1 = f2bf(kv[2 * t + 1] - bf2f(h1));
        u[t] = (unsigned)l0 | ((unsigned)l1 << 16);
      }
    }
    unsigned short* base = part < 4 ? (lo ? K1lo : K1hi) : (lo ? K2lo : K2hi);
    uint4* dst = (uint4*)(base + r * 16);
    dst[0] = make_uint4(u[0], u[1], u[2], u[3]);
    dst[1] = make_uint4(u[4], u[5], u[6], u[7]);
  }
}

// ---------------------------------------------------------------------------
// Phase 2: V projection as bf16 MFMA GEMM (unchanged, verified).
// ---------------------------------------------------------------------------
__global__ __launch_bounds__(256) void v_gemm(const unsigned short* __restrict__ Wcat,
                                              const unsigned short* __restrict__ Xlk,
                                              unsigned short* __restrict__ vbf) {
  __shared__ short As[128 * 64];
  __shared__ short Bs[64 * 64];
  const int tid  = threadIdx.x;
  const int b    = blockIdx.z;
  const int cc0  = blockIdx.x * 128;
  const int l0   = blockIdx.y * 64;
  const int wid  = tid >> 6, lane = tid & 63;
  const int wcc  = (wid >> 1) * 64;
  const int wl   = (wid & 1) * 32;
  const int lrow = lane & 15, quad = lane >> 4;
  floatx4 acc[4][2] = {};
  const unsigned short* wsrc = Wcat + (size_t)cc0 * 512;
  const unsigned short* xsrc = Xlk + ((size_t)b * Lc + l0) * 512;
  int s_off[4], g_off[4];
#pragma unroll
  for (int r = 0; r < 4; ++r) {
    const int idx = r * 256 + tid;
    const int row = idx >> 3, ch = idx & 7;
    s_off[r] = row * 64 + (ch ^ (row & 7)) * 8;
    g_off[r] = row * 512 + ch * 8;
  }
  short8 ar[4], br[2];
#pragma unroll
  for (int r = 0; r < 4; ++r) ar[r] = *(const short8*)(wsrc + g_off[r]);
#pragma unroll
  for (int r = 0; r < 2; ++r) br[r] = *(const short8*)(xsrc + g_off[r]);
  for (int k0 = 0; k0 < 512; k0 += 64) {
    __syncthreads();
#pragma unroll
    for (int r = 0; r < 4; ++r) *(short8*)&As[s_off[r]] = ar[r];
#pragma unroll
    for (int r = 0; r < 2; ++r) *(short8*)&Bs[s_off[r]] = br[r];
    __syncthreads();
    if (k0 + 64 < 512) {
#pragma unroll
      for (int r = 0; r < 4; ++r) ar[r] = *(const short8*)(wsrc + g_off[r] + k0 + 64);
#pragma unroll
      for (int r = 0; r < 2; ++r) br[r] = *(const short8*)(xsrc + g_off[r] + k0 + 64);
    }
#pragma unroll
    for (int kk = 0; kk < 64; kk += 32) {
      const int cb = kk >> 3;  // 0 or 4
      short8 af[4], bf[2];
#pragma unroll
      for (int i = 0; i < 4; ++i)
        af[i] = *(const short8*)&As[(wcc + i * 16 + lrow) * 64 +
                                    ((cb + quad) ^ (lrow & 7)) * 8];
#pragma unroll
      for (int j = 0; j < 2; ++j)
        bf[j] = *(const short8*)&Bs[(wl + j * 16 + lrow) * 64 +
                                    ((cb + quad) ^ (lrow & 7)) * 8];
#pragma unroll
      for (int i = 0; i < 4; ++i)
#pragma unroll
        for (int j = 0; j < 2; ++j)
          acc[i][j] = __builtin_amdgcn_mfma_f32_16x16x32_bf16(af[i], bf[j], acc[i][j], 0, 0, 0);
    }
  }
#pragma unroll
  for (int i = 0; i < 4; ++i) {
    const int ccb = cc0 + wcc + i * 16 + quad * 4;
#pragma unroll
    for (int j = 0; j < 2; ++j) {
      const int l = l0 + wl + j * 16 + lrow;
#pragma unroll
      for (int rg = 0; rg < 4; ++rg)
        vbf[((size_t)b * 512 + ccb + rg) * Lc + l] = f2bf(acc[i][j][rg]);
    }
  }
}

// ---------------------------------------------------------------------------
// Phase 3+4 fused: emax_exp v3 — TLP version. 512 blocks (16 rows each,
// full L) x 1024 threads = 16 waves, each wave owns a 256-l slice ->
// 2 blocks/CU = 8 waves/SIMD (2x the round-8 TLP). __launch_bounds__(1024,8)
// caps VGPR at 64 so both blocks stay resident; 2x unroll (8 staged loads
// ~ 32 VGPR) replaces the 4x that the compiler refused to pipeline (r8:
// VGPR=44 proved re-serialization). Row max/sum combine through 16-entry
// LDS; math and store addresses bit-identical to the verified kernels.
// ---------------------------------------------------------------------------
__global__ __launch_bounds__(1024, 8) void emax_exp(const unsigned short* __restrict__ Qcat,
                                                    const unsigned short* __restrict__ K1hi,
                                                    const unsigned short* __restrict__ K1lo,
                                                    const unsigned short* __restrict__ K2hi,
                                                    const unsigned short* __restrict__ K2lo,
                                                    unsigned short* __restrict__ att,
                                                    float* __restrict__ Ssum) {
  __shared__ unsigned maxb[16];
  __shared__ float    sumb[16];
  const int tid  = threadIdx.x;
  const int wid  = tid >> 6, lane = tid & 63;
  const int lrow = lane & 15, quad = lane >> 4, qsel = quad & 1;
  const int b    = blockIdx.y;
  const int m16  = blockIdx.x * 16;   // 16 rows per block
  const int lbeg = wid * 256;         // 256-l slice per wave
  const size_t kb = (size_t)b * Lc;
  if (tid < 16) { maxb[tid] = 0u; sumb[tid] = 0.f; }
  __syncthreads();
  const short8 afrag = *(const short8*)(Qcat + (kb + m16 + lrow) * 32 + quad * 8);
  // ---- pass 1: hi-only row max, 2x unrolled (4 loads in flight) ----
  float mx[4] = {0.f, 0.f, 0.f, 0.f};
  for (int l0 = lbeg; l0 < lbeg + 256; l0 += 32) {
    short8 b1h[2], b2h[2];
#pragma unroll
    for (int u = 0; u < 2; ++u) {
      const size_t l = kb + l0 + u * 16 + lrow;
      b1h[u] = *(const short8*)(K1hi + l * 16 + qsel * 8);
      b2h[u] = *(const short8*)(K2hi + l * 16 + qsel * 8);
    }
#pragma unroll
    for (int u = 0; u < 2; ++u) {
      const floatx4 er = __builtin_amdgcn_mfma_f32_16x16x32_bf16(afrag, b1h[u], (floatx4){0.f, 0.f, 0.f, 0.f}, 0, 0, 0);
      const floatx4 ei = __builtin_amdgcn_mfma_f32_16x16x32_bf16(afrag, b2h[u], (floatx4){0.f, 0.f, 0.f, 0.f}, 0, 0, 0);
#pragma unroll
      for (int r = 0; r < 4; ++r) {
        float e = er[r] * er[r];
        e = fmaf(ei[r], ei[r], e);
        mx[r] = fmaxf(mx[r], e);
      }
    }
  }
#pragma unroll
  for (int r = 0; r < 4; ++r) {
    float v = mx[r];
#pragma unroll
    for (int off = 1; off < 16; off <<= 1) v = fmaxf(v, __shfl_xor(v, off));
    if (lrow == 0)
      atomicMax(&maxb[quad * 4 + r], __float_as_uint(v));  // E >= 0
  }
  __syncthreads();
  float Mv[4], sum[4] = {};
#pragma unroll
  for (int r = 0; r < 4; ++r) Mv[r] = __uint_as_float(maxb[quad * 4 + r]);
  // ---- pass 2: refined E, exp, att store, 2x unrolled (8 loads in flight) ----
  for (int l0 = lbeg; l0 < lbeg + 256; l0 += 32) {
    short8 b1h[2], b1l[2], b2h[2], b2l[2];
#pragma unroll
    for (int u = 0; u < 2; ++u) {
      const size_t l = kb + l0 + u * 16 + lrow;
      b1h[u] = *(const short8*)(K1hi + l * 16 + qsel * 8);
      b1l[u] = *(const short8*)(K1lo + l * 16 + qsel * 8);
      b2h[u] = *(const short8*)(K2hi + l * 16 + qsel * 8);
      b2l[u] = *(const short8*)(K2lo + l * 16 + qsel * 8);
    }
#pragma unroll
    for (int u = 0; u < 2; ++u) {
      floatx4 er = __builtin_amdgcn_mfma_f32_16x16x32_bf16(afrag, b1l[u], (floatx4){0.f, 0.f, 0.f, 0.f}, 0, 0, 0);
      er = __builtin_amdgcn_mfma_f32_16x16x32_bf16(afrag, b1h[u], er, 0, 0, 0);
      floatx4 ei = __builtin_amdgcn_mfma_f32_16x16x32_bf16(afrag, b2l[u], (floatx4){0.f, 0.f, 0.f, 0.f}, 0, 0, 0);
      ei = __builtin_amdgcn_mfma_f32_16x16x32_bf16(afrag, b2h[u], ei, 0, 0, 0);
#pragma unroll
      for (int r = 0; r < 4; ++r) {
        float e = er[r] * er[r];
        e = fmaf(ei[r], ei[r], e);
        const float wgt = __expf(e - Mv[r]);
        sum[r] += wgt;
        att[(kb + m16 + quad * 4 + r) * Lc + l0 + u * 16 + lrow] = f2bf(wgt);
      }
    }
  }
#pragma unroll
  for (int r = 0; r < 4; ++r) {
    float v = sum[r];
#pragma unroll
    for (int off = 1; off < 16; off <<= 1) v += __shfl_xor(v, off);
    if (lrow == 0) atomicAdd(&sumb[quad * 4 + r], v);
  }
  __syncthreads();
  if (tid < 16) Ssum[kb + m16 + tid] = sumb[tid];
}

// ---------------------------------------------------------------------------
// Phase 5: PV GEMM v3 (unchanged, verified round-7): 1024 threads, 4-way
// split-K, K=128 tiles, 2 x 64 KB DMA buffers, one barrier per phase.
// ---------------------------------------------------------------------------
__device__ __forceinline__ void pv_stage128(const unsigned short* __restrict__ vsrc,
                                            const unsigned short* __restrict__ asrc,
                                            short* lds_buf, int k0, int wid, int lane) {
  const int rsub = lane >> 4;          // 0..3: row within 4-row block
  const int cs   = lane & 15;          // LDS chunk position within 256B row
#pragma unroll
  for (int t = 0; t < 4; ++t) {
    const int q    = wid * 4 + t;      // block id 0..63 (1 KB each)
    const int tile = q >> 5;           // 0 = A(v), 1 = B(att)
    const int j    = q & 31;           // 4-row group within tile
    const int row  = j * 4 + rsub;
    const int gch  = cs ^ (row & 7);   // inverse-swizzled global k-chunk
    const unsigned short* g =
        (tile == 0 ? vsrc : asrc) + (size_t)row * Lc + k0 + gch * 8;
    short* l = lds_buf + tile * 16384 + j * 512;  // wave-uniform dest base
    __builtin_amdgcn_global_load_lds(
        (const __attribute__((address_space(1))) void*)g,
        (__attribute__((address_space(3))) void*)l, 16, 0, 0);
  }
}

__device__ __forceinline__ void pv_compute128(const short* __restrict__ As,
                                              const short* __restrict__ Bs,
                                              int cb, int wcc, int wm, int lrow, int quad,
                                              floatx4 (&acc)[4][4]) {
  short8 af[4], bf[4];
#pragma unroll
  for (int i = 0; i < 4; ++i)
    af[i] = *(const short8*)&As[(wcc + i * 16 + lrow) * 128 +
                                ((cb + quad) ^ (lrow & 7)) * 8];
#pragma unroll
  for (int j = 0; j < 4; ++j)
    bf[j] = *(const short8*)&Bs[(wm + j * 16 + lrow) * 128 +
                                ((cb + quad) ^ (lrow & 7)) * 8];
#pragma unroll
  for (int i = 0; i < 4; ++i)
#pragma unroll
    for (int j = 0; j < 4; ++j)
      acc[i][j] = __builtin_amdgcn_mfma_f32_16x16x32_bf16(af[i], bf[j], acc[i][j], 0, 0, 0);
}

__global__ __launch_bounds__(1024, 1) void pv_gemm(const unsigned short* __restrict__ v,
                                                   const unsigned short* __restrict__ att,
                                                   const float* __restrict__ Ssum,
                                                   const float* __restrict__ x,
                                                   const float* __restrict__ gamma,
                                                   float* __restrict__ out) {
  // 128 KB dynamic: 2 buffers x {A 128x128 | B 128x128} bf16, XOR-swizzled.
  extern __shared__ short smem[];
  // XCD-aware bijective swizzle: 256 blocks, XCD k gets contiguous work ids.
  const int flat = blockIdx.x;
  const int swz  = (flat & 7) * 32 + (flat >> 3);
  const int b    = swz >> 7;
  const int rem  = swz & 127;
  const int m0   = (rem >> 2) * 128;   // 32 m-panels
  const int cc0  = (rem & 3) * 128;    // 4 cc-panels
  const int tid  = threadIdx.x;
  const int wid  = tid >> 6, lane = tid & 63;
  const int g    = wid >> 2;           // split-K group 0..3
  const int w4   = wid & 3;
  const int wcc  = (w4 >> 1) * 64;
  const int wm   = (w4 & 1) * 64;
  const int lrow = lane & 15, quad = lane >> 4;
  const int cb   = g * 4;              // k-chunk base (of 16 chunks)
  floatx4 acc[4][4] = {};
  const unsigned short* vsrc = v   + ((size_t)b * 512 + cc0) * Lc;
  const unsigned short* asrc = att + ((size_t)b * Lc + m0) * Lc;
  // Prologue: DMA tile 0 into buf0.
  pv_stage128(vsrc, asrc, smem, 0, wid, lane);
  for (int p = 0; p < 32; ++p) {
    asm volatile("s_waitcnt vmcnt(0)" ::: "memory");
    __builtin_amdgcn_s_barrier();       // tile p complete; p-1 compute done
    __builtin_amdgcn_sched_barrier(0);
    if (p + 1 < 32)
      pv_stage128(vsrc, asrc, smem + ((p + 1) & 1) * 32768, (p + 1) * 128, wid, lane);
    __builtin_amdgcn_sched_barrier(0);
    pv_compute128(smem + (p & 1) * 32768, smem + (p & 1) * 32768 + 16384,
                  cb, wcc, wm, lrow, quad, acc);
    __builtin_amdgcn_sched_barrier(0);
  }
  __syncthreads();  // all computes done before smem reuse for reduction
  float* red = (float*)smem;  // 32768 floats = 128 KB
  // Round 1: g1 -> red[0..16383], g3 -> red[16384..32767]
  if (g == 1 || g == 3) {
    float* dst = red + (g == 3 ? 16384 : 0);
#pragma unroll
    for (int i = 0; i < 4; ++i)
#pragma unroll
      for (int j = 0; j < 4; ++j) {
        const int tq = i * 4 + j;
        *(floatx4*)&dst[((w4 * 64 + lane) * 16 + (tq ^ (lane & 15))) * 4] = acc[i][j];
      }
  }
  __syncthreads();
  if (g == 0 || g == 2) {
    const float* src = red + (g == 2 ? 16384 : 0);
#pragma unroll
    for (int i = 0; i < 4; ++i)
#pragma unroll
      for (int j = 0; j < 4; ++j) {
        const int tq = i * 4 + j;
        const floatx4 o = *(const floatx4*)&src[((w4 * 64 + lane) * 16 + (tq ^ (lane & 15))) * 4];
        acc[i][j] += o;
      }
  }
  __syncthreads();
  // Round 2: g2 -> red[0..16383]
  if (g == 2) {
#pragma unroll
    for (int i = 0; i < 4; ++i)
#pragma unroll
      for (int j = 0; j < 4; ++j) {
        const int tq = i * 4 + j;
        *(floatx4*)&red[((w4 * 64 + lane) * 16 + (tq ^ (lane & 15))) * 4] = acc[i][j];
      }
  }
  __syncthreads();
  if (g == 0) {
#pragma unroll
    for (int i = 0; i < 4; ++i)
#pragma unroll
      for (int j = 0; j < 4; ++j) {
        const int tq = i * 4 + j;
        const floatx4 o = *(const floatx4*)&red[((w4 * 64 + lane) * 16 + (tq ^ (lane & 15))) * 4];
        acc[i][j] += o;
      }
    const float gm = gamma[0];
    float svj[4];
#pragma unroll
    for (int j = 0; j < 4; ++j)
      svj[j] = gm / Ssum[(size_t)b * Lc + m0 + wm + j * 16 + lrow];
#pragma unroll
    for (int i = 0; i < 4; ++i) {
      const int ccb = cc0 + wcc + i * 16 + quad * 4;
#pragma unroll
      for (int j = 0; j < 4; ++j) {
        const int m = m0 + wm + j * 16 + lrow;
#pragma unroll
        for (int rg = 0; rg < 4; ++rg) {
          const int cc   = ccb + rg;
          const int comp = cc >> 8, c = cc & 255;
          const size_t idx = (((size_t)comp * Bc + b) * CGc + c) * Lc + m;
          out[idx] = svj[j] * acc[i][j][rg] + x[idx];
        }
      }
    }
  }
}

// ---------------------------------------------------------------------------
extern "C" void kernel_launch(void* const* d_in, const int* in_sizes, int n_in,
                              void* d_out, int out_size, void* d_ws, size_t ws_size,
                              hipStream_t stream) {
  const float* x     = (const float*)d_in[0];
  const float* wq    = (const float*)d_in[1];
  const float* wk    = (const float*)d_in[2];
  const float* wv    = (const float*)d_in[3];
  const float* gamma = (const float*)d_in[4];
  float* out = (float*)d_out;

  // Workspace (~78.7 MB). Xlk aliases att (stream-ordered: v_gemm reads Xlk
  // before emax_exp overwrites the region with att). q/kk/Mrow slots
  // retained for layout stability (unused). Ssum needs no init (direct
  // store from emax_exp).
  float* q    = (float*)d_ws;                         // 131072 (unused)
  float* kk   = q    + (size_t)Bc * Lc * 16;          // 131072 (unused)
  float* Mrow = kk   + (size_t)Bc * Lc * 16;          // 8192 (unused)
  float* Ssum = Mrow + (size_t)Bc * Lc;               // 8192
  unsigned short* vbf  = (unsigned short*)(Ssum + (size_t)Bc * Lc);  // 2*512*4096
  unsigned short* att  = vbf + (size_t)Bc * 512 * Lc;                // 2*4096*4096
  unsigned short* Xlk  = att;                                        // alias (8.4MB)
  unsigned short* Qcat = att + (size_t)Bc * Lc * Lc;                 // 8192*32
  unsigned short* K1hi = Qcat + (size_t)Bc * Lc * 32;                // 8192*16
  unsigned short* K1lo = K1hi + (size_t)Bc * Lc * 16;
  unsigned short* K2hi = K1lo + (size_t)Bc * Lc * 16;
  unsigned short* K2lo = K2hi + (size_t)Bc * Lc * 16;
  unsigned short* Wcat = K2lo + (size_t)Bc * Lc * 16;                // 512*512

  wcat_pack<<<dim3((512 * 512) / 256), 256, 0, stream>>>(wv, Wcat);
  qk_projpack<<<dim3(Lc / 32, Bc), 256, 0, stream>>>(x, wq, wk, Qcat, K1hi, K1lo, K2hi, K2lo);
  xT_pack<<<dim3(Lc / 64, 8, Bc), 256, 0, stream>>>(x, Xlk);
  v_gemm<<<dim3(512 / 128, Lc / 64, Bc), 256, 0, stream>>>(Wcat, Xlk, vbf);
  emax_exp<<<dim3(Lc / 16, Bc), 1024, 0, stream>>>(Qcat, K1hi, K1lo, K2hi, K2lo, att, Ssum);
  pv_gemm<<<dim3(256), 1024, 2 * 32768 * sizeof(short), stream>>>(vbf, att, Ssum, x, gamma, out);
}

// Round 10
// 170.499 us; speedup vs baseline: 1.1307x; 1.0894x over previous
//
#include <hip/hip_runtime.h>
#include <cstdint>

// Shapes (fixed by the problem): B=2, C=64, G=4 -> CG=256, DQK=8, L=64*64=4096
constexpr int Bc  = 2;
constexpr int CGc = 256;
constexpr int Dc  = 8;
constexpr int Lc  = 4096;

typedef __attribute__((ext_vector_type(8))) short short8;
typedef __attribute__((ext_vector_type(4))) float floatx4;

__device__ inline unsigned short f2bf(float f) {
  union { float f; unsigned u; } v; v.f = f;
  unsigned r = v.u + 0x7fffu + ((v.u >> 16) & 1u);
  return (unsigned short)(r >> 16);
}
__device__ inline float bf2f(unsigned short h) {
  return __uint_as_float((unsigned)h << 16);
}

// ---------------------------------------------------------------------------
// Phase 0: Wcat[cc][k] bf16 = [[Wr, -Wi], [Wi, Wr]] (512x512) for v_gemm.
// ---------------------------------------------------------------------------
__global__ __launch_bounds__(256) void wcat_pack(const float* __restrict__ wv,
                                                 unsigned short* __restrict__ Wcat) {
  const int i  = blockIdx.x * 256 + threadIdx.x;  // 0..262143
  const int cc = i >> 9, k = i & 511;
  const int co = cc >> 8, c = cc & 255, ci = k >> 8, cin = k & 255;
  const float wr = wv[(size_t)c * CGc + cin];
  const float wi = wv[(size_t)(CGc + c) * CGc + cin];
  const float val = co == 0 ? (ci == 0 ? wr : -wi) : (ci == 0 ? wi : wr);
  Wcat[i] = f2bf(val);
}

// ---------------------------------------------------------------------------
// Phase 0b: LDS-transpose x -> Xlk[b][l][cin2] bf16 (cin2 = comp*256+cin).
// ---------------------------------------------------------------------------
__global__ __launch_bounds__(256) void xT_pack(const float* __restrict__ x,
                                               unsigned short* __restrict__ Xlk) {
  __shared__ float xs[64][65];
  const int tid = threadIdx.x;
  const int b   = blockIdx.z;
  const int l0  = blockIdx.x * 64;
  const int c0  = blockIdx.y * 64;
  const int lt  = tid & 63, r4 = tid >> 6;
#pragma unroll
  for (int p = 0; p < 16; ++p) {
    const int row  = p * 4 + r4;
    const int cin2 = c0 + row;
    const int comp = cin2 >> 8, cin = cin2 & 255;
    xs[row][lt] = x[((size_t)(comp * Bc + b) * CGc + cin) * Lc + l0 + lt];
  }
  __syncthreads();
#pragma unroll
  for (int p = 0; p < 16; ++p) {
    const int lr = p * 4 + r4;
    Xlk[((size_t)b * Lc + l0 + lr) * 512 + c0 + lt] = f2bf(xs[lt][lr]);
  }
}

// ---------------------------------------------------------------------------
// Phase 1 (fused) v2: complex Q/K projection + split-bf16 packing, with
// in-block 4-way cin-split for occupancy. 1024 threads = 4 cin-groups x
// (8d x 32m): each group accumulates a 64-cin partial (round-9 profile:
// 42.6 us at 1 wave/SIMD, VALUBusy 10% = pure load-latency exposure ->
// 4 waves/SIMD + 4x MLP). Partials combine through padded LDS
// ([4][32][17], conflict-free); the 256-thread pack stage sums
// (((p0+p1)+p2)+p3) and packs exactly as the verified round-6 code.
// ---------------------------------------------------------------------------
__global__ __launch_bounds__(1024, 4) void qk_projpack(const float* __restrict__ x,
                                                       const float* __restrict__ wq,
                                                       const float* __restrict__ wk,
                                                       unsigned short* __restrict__ Qcat,
                                                       unsigned short* __restrict__ K1hi,
                                                       unsigned short* __restrict__ K1lo,
                                                       unsigned short* __restrict__ K2hi,
                                                       unsigned short* __restrict__ K2lo) {
  __shared__ float ws[4 * Dc * CGc];   // 32 KB: wq_r | wq_i | wk_r | wk_i
  __shared__ float pq[4][32][17];      // 8.5 KB padded q partials
  __shared__ float pk[4][32][17];      // 8.5 KB padded k partials
  const int tid = threadIdx.x;
  const int b   = blockIdx.y;
  for (int i = tid; i < 2 * Dc * CGc; i += 1024) {
    ws[i]                 = wq[i];
    ws[2 * Dc * CGc + i]  = wk[i];
  }
  __syncthreads();
  const int cg  = tid >> 8;   // cin group 0..3
  const int sub = tid & 255;
  const int d   = sub >> 5;   // 0..7
  const int ml  = sub & 31;   // 0..31
  const int m   = blockIdx.x * 32 + ml;
  const int c0  = cg * 64;
  const float* xr = x + ((size_t)(0 * Bc + b) * CGc + c0) * Lc + m;
  const float* xi = x + ((size_t)(1 * Bc + b) * CGc + c0) * Lc + m;
  const float* wqr = ws + d * CGc + c0;
  const float* wqi = ws + (Dc + d) * CGc + c0;
  const float* wkr = ws + 2 * Dc * CGc + d * CGc + c0;
  const float* wki = ws + 2 * Dc * CGc + (Dc + d) * CGc + c0;
  float qer = 0.f, qei = 0.f, ker = 0.f, kei = 0.f;
#pragma unroll 4
  for (int cin = 0; cin < 64; ++cin) {
    const float vr = xr[(size_t)cin * Lc];
    const float vi = xi[(size_t)cin * Lc];
    const float a1 = wqr[cin], b1 = wqi[cin];
    qer = fmaf(a1, vr, qer); qer = fmaf(-b1, vi, qer);
    qei = fmaf(a1, vi, qei); qei = fmaf(b1, vr, qei);
    const float a2 = wkr[cin], b2 = wki[cin];
    ker = fmaf(a2, vr, ker); ker = fmaf(-b2, vi, ker);
    kei = fmaf(a2, vi, kei); kei = fmaf(b2, vr, kei);
  }
  pq[cg][ml][d]     = qer;
  pq[cg][ml][8 + d] = qei;
  pk[cg][ml][d]     = ker;
  pk[cg][ml][8 + d] = kei;
  __syncthreads();
  // --- pack stage (first 256 threads; sums 4 partials, then verified pack) ---
  if (tid < 256) {
    const int part = tid >> 5;       // 0..7
    const int rl   = tid & 31;       // local row
    const size_t r = (size_t)b * Lc + blockIdx.x * 32 + rl;
    if (part < 2) {
      unsigned u[8];
#pragma unroll
      for (int t = 0; t < 8; ++t) {
        const float v0 = ((pq[0][rl][2 * t] + pq[1][rl][2 * t]) + pq[2][rl][2 * t]) + pq[3][rl][2 * t];
        const float v1 = ((pq[0][rl][2 * t + 1] + pq[1][rl][2 * t + 1]) + pq[2][rl][2 * t + 1]) + pq[3][rl][2 * t + 1];
        const unsigned short h0 = f2bf(v0), h1 = f2bf(v1);
        if (part == 0) {
          u[t] = (unsigned)h0 | ((unsigned)h1 << 16);
        } else {
          const unsigned short l0 = f2bf(v0 - bf2f(h0));
          const unsigned short l1 = f2bf(v1 - bf2f(h1));
          u[t] = (unsigned)l0 | ((unsigned)l1 << 16);
        }
      }
      uint4* dst = (uint4*)(Qcat + r * 32 + part * 16);
      dst[0] = make_uint4(u[0], u[1], u[2], u[3]);
      dst[1] = make_uint4(u[4], u[5], u[6], u[7]);
    } else if (part < 6) {
      float ksum[16];
#pragma unroll
      for (int e = 0; e < 16; ++e)
        ksum[e] = ((pk[0][rl][e] + pk[1][rl][e]) + pk[2][rl][e]) + pk[3][rl][e];
      float kv[16];
      if (part < 4) {
#pragma unroll
        for (int e = 0; e < 8; ++e) { kv[e] = ksum[e]; kv[8 + e] = -ksum[8 + e]; }
      } else {
#pragma unroll
        for (int e = 0; e < 8; ++e) { kv[e] = ksum[8 + e]; kv[8 + e] = ksum[e]; }
      }
      const int lo = part & 1;
      unsigned u[8];
#pragma unroll
      for (int t = 0; t < 8; ++t) {
        const unsigned short h0 = f2bf(kv[2 * t]), h1 = f2bf(kv[2 * t + 1]);
        if (!lo) {
          u[t] = (unsigned)h0 | ((unsigned)h1 << 16);
        } else {
          const unsigned short l0 = f2bf(kv[2 * t] - bf2f(h0));
          const unsigned short l1 = f2bf(kv[2 * t + 1] - bf2f(h1));
          u[t] = (unsigned)l0 | ((unsigned)l1 << 16);
        }
      }
      unsigned short* base = part < 4 ? (lo ? K1lo : K1hi) : (lo ? K2lo : K2hi);
      uint4* dst = (uint4*)(base + r * 16);
      dst[0] = make_uint4(u[0], u[1], u[2], u[3]);
      dst[1] = make_uint4(u[4], u[5], u[6], u[7]);
    }
  }
}

// ---------------------------------------------------------------------------
// Phase 2: V projection as bf16 MFMA GEMM (unchanged, verified).
// ---------------------------------------------------------------------------
__global__ __launch_bounds__(256) void v_gemm(const unsigned short* __restrict__ Wcat,
                                              const unsigned short* __restrict__ Xlk,
                                              unsigned short* __restrict__ vbf) {
  __shared__ short As[128 * 64];
  __shared__ short Bs[64 * 64];
  const int tid  = threadIdx.x;
  const int b    = blockIdx.z;
  const int cc0  = blockIdx.x * 128;
  const int l0   = blockIdx.y * 64;
  const int wid  = tid >> 6, lane = tid & 63;
  const int wcc  = (wid >> 1) * 64;
  const int wl   = (wid & 1) * 32;
  const int lrow = lane & 15, quad = lane >> 4;
  floatx4 acc[4][2] = {};
  const unsigned short* wsrc = Wcat + (size_t)cc0 * 512;
  const unsigned short* xsrc = Xlk + ((size_t)b * Lc + l0) * 512;
  int s_off[4], g_off[4];
#pragma unroll
  for (int r = 0; r < 4; ++r) {
    const int idx = r * 256 + tid;
    const int row = idx >> 3, ch = idx & 7;
    s_off[r] = row * 64 + (ch ^ (row & 7)) * 8;
    g_off[r] = row * 512 + ch * 8;
  }
  short8 ar[4], br[2];
#pragma unroll
  for (int r = 0; r < 4; ++r) ar[r] = *(const short8*)(wsrc + g_off[r]);
#pragma unroll
  for (int r = 0; r < 2; ++r) br[r] = *(const short8*)(xsrc + g_off[r]);
  for (int k0 = 0; k0 < 512; k0 += 64) {
    __syncthreads();
#pragma unroll
    for (int r = 0; r < 4; ++r) *(short8*)&As[s_off[r]] = ar[r];
#pragma unroll
    for (int r = 0; r < 2; ++r) *(short8*)&Bs[s_off[r]] = br[r];
    __syncthreads();
    if (k0 + 64 < 512) {
#pragma unroll
      for (int r = 0; r < 4; ++r) ar[r] = *(const short8*)(wsrc + g_off[r] + k0 + 64);
#pragma unroll
      for (int r = 0; r < 2; ++r) br[r] = *(const short8*)(xsrc + g_off[r] + k0 + 64);
    }
#pragma unroll
    for (int kk = 0; kk < 64; kk += 32) {
      const int cb = kk >> 3;  // 0 or 4
      short8 af[4], bf[2];
#pragma unroll
      for (int i = 0; i < 4; ++i)
        af[i] = *(const short8*)&As[(wcc + i * 16 + lrow) * 64 +
                                    ((cb + quad) ^ (lrow & 7)) * 8];
#pragma unroll
      for (int j = 0; j < 2; ++j)
        bf[j] = *(const short8*)&Bs[(wl + j * 16 + lrow) * 64 +
                                    ((cb + quad) ^ (lrow & 7)) * 8];
#pragma unroll
      for (int i = 0; i < 4; ++i)
#pragma unroll
        for (int j = 0; j < 2; ++j)
          acc[i][j] = __builtin_amdgcn_mfma_f32_16x16x32_bf16(af[i], bf[j], acc[i][j], 0, 0, 0);
    }
  }
#pragma unroll
  for (int i = 0; i < 4; ++i) {
    const int ccb = cc0 + wcc + i * 16 + quad * 4;
#pragma unroll
    for (int j = 0; j < 2; ++j) {
      const int l = l0 + wl + j * 16 + lrow;
#pragma unroll
      for (int rg = 0; rg < 4; ++rg)
        vbf[((size_t)b * 512 + ccb + rg) * Lc + l] = f2bf(acc[i][j][rg]);
    }
  }
}

// ---------------------------------------------------------------------------
// Phase 3+4 fused: emax_exp v3 (unchanged, verified round-9): 512 blocks
// x 1024 threads, 8 waves/SIMD, 2x unroll, LDS max/sum combine.
// ---------------------------------------------------------------------------
__global__ __launch_bounds__(1024, 8) void emax_exp(const unsigned short* __restrict__ Qcat,
                                                    const unsigned short* __restrict__ K1hi,
                                                    const unsigned short* __restrict__ K1lo,
                                                    const unsigned short* __restrict__ K2hi,
                                                    const unsigned short* __restrict__ K2lo,
                                                    unsigned short* __restrict__ att,
                                                    float* __restrict__ Ssum) {
  __shared__ unsigned maxb[16];
  __shared__ float    sumb[16];
  const int tid  = threadIdx.x;
  const int wid  = tid >> 6, lane = tid & 63;
  const int lrow = lane & 15, quad = lane >> 4, qsel = quad & 1;
  const int b    = blockIdx.y;
  const int m16  = blockIdx.x * 16;   // 16 rows per block
  const int lbeg = wid * 256;         // 256-l slice per wave
  const size_t kb = (size_t)b * Lc;
  if (tid < 16) { maxb[tid] = 0u; sumb[tid] = 0.f; }
  __syncthreads();
  const short8 afrag = *(const short8*)(Qcat + (kb + m16 + lrow) * 32 + quad * 8);
  // ---- pass 1: hi-only row max, 2x unrolled (4 loads in flight) ----
  float mx[4] = {0.f, 0.f, 0.f, 0.f};
  for (int l0 = lbeg; l0 < lbeg + 256; l0 += 32) {
    short8 b1h[2], b2h[2];
#pragma unroll
    for (int u = 0; u < 2; ++u) {
      const size_t l = kb + l0 + u * 16 + lrow;
      b1h[u] = *(const short8*)(K1hi + l * 16 + qsel * 8);
      b2h[u] = *(const short8*)(K2hi + l * 16 + qsel * 8);
    }
#pragma unroll
    for (int u = 0; u < 2; ++u) {
      const floatx4 er = __builtin_amdgcn_mfma_f32_16x16x32_bf16(afrag, b1h[u], (floatx4){0.f, 0.f, 0.f, 0.f}, 0, 0, 0);
      const floatx4 ei = __builtin_amdgcn_mfma_f32_16x16x32_bf16(afrag, b2h[u], (floatx4){0.f, 0.f, 0.f, 0.f}, 0, 0, 0);
#pragma unroll
      for (int r = 0; r < 4; ++r) {
        float e = er[r] * er[r];
        e = fmaf(ei[r], ei[r], e);
        mx[r] = fmaxf(mx[r], e);
      }
    }
  }
#pragma unroll
  for (int r = 0; r < 4; ++r) {
    float v = mx[r];
#pragma unroll
    for (int off = 1; off < 16; off <<= 1) v = fmaxf(v, __shfl_xor(v, off));
    if (lrow == 0)
      atomicMax(&maxb[quad * 4 + r], __float_as_uint(v));  // E >= 0
  }
  __syncthreads();
  float Mv[4], sum[4] = {};
#pragma unroll
  for (int r = 0; r < 4; ++r) Mv[r] = __uint_as_float(maxb[quad * 4 + r]);
  // ---- pass 2: refined E, exp, att store, 2x unrolled (8 loads in flight) ----
  for (int l0 = lbeg; l0 < lbeg + 256; l0 += 32) {
    short8 b1h[2], b1l[2], b2h[2], b2l[2];
#pragma unroll
    for (int u = 0; u < 2; ++u) {
      const size_t l = kb + l0 + u * 16 + lrow;
      b1h[u] = *(const short8*)(K1hi + l * 16 + qsel * 8);
      b1l[u] = *(const short8*)(K1lo + l * 16 + qsel * 8);
      b2h[u] = *(const short8*)(K2hi + l * 16 + qsel * 8);
      b2l[u] = *(const short8*)(K2lo + l * 16 + qsel * 8);
    }
#pragma unroll
    for (int u = 0; u < 2; ++u) {
      floatx4 er = __builtin_amdgcn_mfma_f32_16x16x32_bf16(afrag, b1l[u], (floatx4){0.f, 0.f, 0.f, 0.f}, 0, 0, 0);
      er = __builtin_amdgcn_mfma_f32_16x16x32_bf16(afrag, b1h[u], er, 0, 0, 0);
      floatx4 ei = __builtin_amdgcn_mfma_f32_16x16x32_bf16(afrag, b2l[u], (floatx4){0.f, 0.f, 0.f, 0.f}, 0, 0, 0);
      ei = __builtin_amdgcn_mfma_f32_16x16x32_bf16(afrag, b2h[u], ei, 0, 0, 0);
#pragma unroll
      for (int r = 0; r < 4; ++r) {
        float e = er[r] * er[r];
        e = fmaf(ei[r], ei[r], e);
        const float wgt = __expf(e - Mv[r]);
        sum[r] += wgt;
        att[(kb + m16 + quad * 4 + r) * Lc + l0 + u * 16 + lrow] = f2bf(wgt);
      }
    }
  }
#pragma unroll
  for (int r = 0; r < 4; ++r) {
    float v = sum[r];
#pragma unroll
    for (int off = 1; off < 16; off <<= 1) v += __shfl_xor(v, off);
    if (lrow == 0) atomicAdd(&sumb[quad * 4 + r], v);
  }
  __syncthreads();
  if (tid < 16) Ssum[kb + m16 + tid] = sumb[tid];
}

// ---------------------------------------------------------------------------
// Phase 5: PV GEMM v3.1 — main loop unchanged (verified round-7); split-K
// reduction re-addressed LANE-CONTIGUOUS ((tq*256 + w4*64 + lane)*4 floats:
// each vector op covers 1 KB contiguous = zero bank conflicts; round-9
// profile showed 4.19M conflicts with the old 1024B-per-lane stride).
// Same values, same (w4,lane) correspondence -> bit-identical sums.
// ---------------------------------------------------------------------------
__device__ __forceinline__ void pv_stage128(const unsigned short* __restrict__ vsrc,
                                            const unsigned short* __restrict__ asrc,
                                            short* lds_buf, int k0, int wid, int lane) {
  const int rsub = lane >> 4;          // 0..3: row within 4-row block
  const int cs   = lane & 15;          // LDS chunk position within 256B row
#pragma unroll
  for (int t = 0; t < 4; ++t) {
    const int q    = wid * 4 + t;      // block id 0..63 (1 KB each)
    const int tile = q >> 5;           // 0 = A(v), 1 = B(att)
    const int j    = q & 31;           // 4-row group within tile
    const int row  = j * 4 + rsub;
    const int gch  = cs ^ (row & 7);   // inverse-swizzled global k-chunk
    const unsigned short* g =
        (tile == 0 ? vsrc : asrc) + (size_t)row * Lc + k0 + gch * 8;
    short* l = lds_buf + tile * 16384 + j * 512;  // wave-uniform dest base
    __builtin_amdgcn_global_load_lds(
        (const __attribute__((address_space(1))) void*)g,
        (__attribute__((address_space(3))) void*)l, 16, 0, 0);
  }
}

__device__ __forceinline__ void pv_compute128(const short* __restrict__ As,
                                              const short* __restrict__ Bs,
                                              int cb, int wcc, int wm, int lrow, int quad,
                                              floatx4 (&acc)[4][4]) {
  short8 af[4], bf[4];
#pragma unroll
  for (int i = 0; i < 4; ++i)
    af[i] = *(const short8*)&As[(wcc + i * 16 + lrow) * 128 +
                                ((cb + quad) ^ (lrow & 7)) * 8];
#pragma unroll
  for (int j = 0; j < 4; ++j)
    bf[j] = *(const short8*)&Bs[(wm + j * 16 + lrow) * 128 +
                                ((cb + quad) ^ (lrow & 7)) * 8];
#pragma unroll
  for (int i = 0; i < 4; ++i)
#pragma unroll
    for (int j = 0; j < 4; ++j)
      acc[i][j] = __builtin_amdgcn_mfma_f32_16x16x32_bf16(af[i], bf[j], acc[i][j], 0, 0, 0);
}

__global__ __launch_bounds__(1024, 1) void pv_gemm(const unsigned short* __restrict__ v,
                                                   const unsigned short* __restrict__ att,
                                                   const float* __restrict__ Ssum,
                                                   const float* __restrict__ x,
                                                   const float* __restrict__ gamma,
                                                   float* __restrict__ out) {
  // 128 KB dynamic: 2 buffers x {A 128x128 | B 128x128} bf16, XOR-swizzled.
  extern __shared__ short smem[];
  // XCD-aware bijective swizzle: 256 blocks, XCD k gets contiguous work ids.
  const int flat = blockIdx.x;
  const int swz  = (flat & 7) * 32 + (flat >> 3);
  const int b    = swz >> 7;
  const int rem  = swz & 127;
  const int m0   = (rem >> 2) * 128;   // 32 m-panels
  const int cc0  = (rem & 3) * 128;    // 4 cc-panels
  const int tid  = threadIdx.x;
  const int wid  = tid >> 6, lane = tid & 63;
  const int g    = wid >> 2;           // split-K group 0..3
  const int w4   = wid & 3;
  const int wcc  = (w4 >> 1) * 64;
  const int wm   = (w4 & 1) * 64;
  const int lrow = lane & 15, quad = lane >> 4;
  const int cb   = g * 4;              // k-chunk base (of 16 chunks)
  floatx4 acc[4][4] = {};
  const unsigned short* vsrc = v   + ((size_t)b * 512 + cc0) * Lc;
  const unsigned short* asrc = att + ((size_t)b * Lc + m0) * Lc;
  // Prologue: DMA tile 0 into buf0.
  pv_stage128(vsrc, asrc, smem, 0, wid, lane);
  for (int p = 0; p < 32; ++p) {
    asm volatile("s_waitcnt vmcnt(0)" ::: "memory");
    __builtin_amdgcn_s_barrier();       // tile p complete; p-1 compute done
    __builtin_amdgcn_sched_barrier(0);
    if (p + 1 < 32)
      pv_stage128(vsrc, asrc, smem + ((p + 1) & 1) * 32768, (p + 1) * 128, wid, lane);
    __builtin_amdgcn_sched_barrier(0);
    pv_compute128(smem + (p & 1) * 32768, smem + (p & 1) * 32768 + 16384,
                  cb, wcc, wm, lrow, quad, acc);
    __builtin_amdgcn_sched_barrier(0);
  }
  __syncthreads();  // all computes done before smem reuse for reduction
  float* red = (float*)smem;  // 32768 floats = 128 KB
  // Round 1: g1 -> red[0..16383], g3 -> red[16384..32767] (lane-contiguous)
  if (g == 1 || g == 3) {
    float* dst = red + (g == 3 ? 16384 : 0);
#pragma unroll
    for (int i = 0; i < 4; ++i)
#pragma unroll
      for (int j = 0; j < 4; ++j) {
        const int tq = i * 4 + j;
        *(floatx4*)&dst[(tq * 256 + w4 * 64 + lane) * 4] = acc[i][j];
      }
  }
  __syncthreads();
  if (g == 0 || g == 2) {
    const float* src = red + (g == 2 ? 16384 : 0);
#pragma unroll
    for (int i = 0; i < 4; ++i)
#pragma unroll
      for (int j = 0; j < 4; ++j) {
        const int tq = i * 4 + j;
        const floatx4 o = *(const floatx4*)&src[(tq * 256 + w4 * 64 + lane) * 4];
        acc[i][j] += o;
      }
  }
  __syncthreads();
  // Round 2: g2 -> red[0..16383]
  if (g == 2) {
#pragma unroll
    for (int i = 0; i < 4; ++i)
#pragma unroll
      for (int j = 0; j < 4; ++j) {
        const int tq = i * 4 + j;
        *(floatx4*)&red[(tq * 256 + w4 * 64 + lane) * 4] = acc[i][j];
      }
  }
  __syncthreads();
  if (g == 0) {
#pragma unroll
    for (int i = 0; i < 4; ++i)
#pragma unroll
      for (int j = 0; j < 4; ++j) {
        const int tq = i * 4 + j;
        const floatx4 o = *(const floatx4*)&red[(tq * 256 + w4 * 64 + lane) * 4];
        acc[i][j] += o;
      }
    const float gm = gamma[0];
    float svj[4];
#pragma unroll
    for (int j = 0; j < 4; ++j)
      svj[j] = gm / Ssum[(size_t)b * Lc + m0 + wm + j * 16 + lrow];
#pragma unroll
    for (int i = 0; i < 4; ++i) {
      const int ccb = cc0 + wcc + i * 16 + quad * 4;
#pragma unroll
      for (int j = 0; j < 4; ++j) {
        const int m = m0 + wm + j * 16 + lrow;
#pragma unroll
        for (int rg = 0; rg < 4; ++rg) {
          const int cc   = ccb + rg;
          const int comp = cc >> 8, c = cc & 255;
          const size_t idx = (((size_t)comp * Bc + b) * CGc + c) * Lc + m;
          out[idx] = svj[j] * acc[i][j][rg] + x[idx];
        }
      }
    }
  }
}

// ---------------------------------------------------------------------------
extern "C" void kernel_launch(void* const* d_in, const int* in_sizes, int n_in,
                              void* d_out, int out_size, void* d_ws, size_t ws_size,
                              hipStream_t stream) {
  const float* x     = (const float*)d_in[0];
  const float* wq    = (const float*)d_in[1];
  const float* wk    = (const float*)d_in[2];
  const float* wv    = (const float*)d_in[3];
  const float* gamma = (const float*)d_in[4];
  float* out = (float*)d_out;

  // Workspace (~78.7 MB). Xlk aliases att (stream-ordered: v_gemm reads Xlk
  // before emax_exp overwrites the region with att). q/kk/Mrow slots
  // retained for layout stability (unused). Ssum needs no init (direct
  // store from emax_exp).
  float* q    = (float*)d_ws;                         // 131072 (unused)
  float* kk   = q    + (size_t)Bc * Lc * 16;          // 131072 (unused)
  float* Mrow = kk   + (size_t)Bc * Lc * 16;          // 8192 (unused)
  float* Ssum = Mrow + (size_t)Bc * Lc;               // 8192
  unsigned short* vbf  = (unsigned short*)(Ssum + (size_t)Bc * Lc);  // 2*512*4096
  unsigned short* att  = vbf + (size_t)Bc * 512 * Lc;                // 2*4096*4096
  unsigned short* Xlk  = att;                                        // alias (8.4MB)
  unsigned short* Qcat = att + (size_t)Bc * Lc * Lc;                 // 8192*32
  unsigned short* K1hi = Qcat + (size_t)Bc * Lc * 32;                // 8192*16
  unsigned short* K1lo = K1hi + (size_t)Bc * Lc * 16;
  unsigned short* K2hi = K1lo + (size_t)Bc * Lc * 16;
  unsigned short* K2lo = K2hi + (size_t)Bc * Lc * 16;
  unsigned short* Wcat = K2lo + (size_t)Bc * Lc * 16;                // 512*512

  wcat_pack<<<dim3((512 * 512) / 256), 256, 0, stream>>>(wv, Wcat);
  qk_projpack<<<dim3(Lc / 32, Bc), 1024, 0, stream>>>(x, wq, wk, Qcat, K1hi, K1lo, K2hi, K2lo);
  xT_pack<<<dim3(Lc / 64, 8, Bc), 256, 0, stream>>>(x, Xlk);
  v_gemm<<<dim3(512 / 128, Lc / 64, Bc), 256, 0, stream>>>(Wcat, Xlk, vbf);
  emax_exp<<<dim3(Lc / 16, Bc), 1024, 0, stream>>>(Qcat, K1hi, K1lo, K2hi, K2lo, att, Ssum);
  pv_gemm<<<dim3(256), 1024, 2 * 32768 * sizeof(short), stream>>>(vbf, att, Ssum, x, gamma, out);
}

// Round 11
// 168.223 us; speedup vs baseline: 1.1460x; 1.0135x over previous
//
#include <hip/hip_runtime.h>
#include <cstdint>

// Shapes (fixed by the problem): B=2, C=64, G=4 -> CG=256, DQK=8, L=64*64=4096
constexpr int Bc  = 2;
constexpr int CGc = 256;
constexpr int Dc  = 8;
constexpr int Lc  = 4096;

typedef __attribute__((ext_vector_type(8))) short short8;
typedef __attribute__((ext_vector_type(4))) float floatx4;

__device__ inline unsigned short f2bf(float f) {
  union { float f; unsigned u; } v; v.f = f;
  unsigned r = v.u + 0x7fffu + ((v.u >> 16) & 1u);
  return (unsigned short)(r >> 16);
}
__device__ inline float bf2f(unsigned short h) {
  return __uint_as_float((unsigned)h << 16);
}

// ---------------------------------------------------------------------------
// Phase 0 (merged): grid (64, 8, 4), 256 threads.
//   z in {0,1}: xT-transpose x -> Xlk[b=z][l][cin2] bf16 (verified xT_pack).
//   z in {2,3}: Wcat[cc][k] bf16 = [[Wr,-Wi],[Wi,Wr]] (verified wcat_pack;
//               linear block id = ((z-2)*8 + y)*64 + x covers 0..1023).
// Independent input-only stages merged to save one launch gap.
// ---------------------------------------------------------------------------
__global__ __launch_bounds__(256) void prep_pack(const float* __restrict__ x,
                                                 const float* __restrict__ wv,
                                                 unsigned short* __restrict__ Xlk,
                                                 unsigned short* __restrict__ Wcat) {
  const int tid = threadIdx.x;
  const int z   = blockIdx.z;
  if (z >= 2) {
    const int i  = ((((z - 2) * 8 + blockIdx.y) * 64 + blockIdx.x) << 8) + tid;
    const int cc = i >> 9, k = i & 511;
    const int co = cc >> 8, c = cc & 255, ci = k >> 8, cin = k & 255;
    const float wr = wv[(size_t)c * CGc + cin];
    const float wi = wv[(size_t)(CGc + c) * CGc + cin];
    const float val = co == 0 ? (ci == 0 ? wr : -wi) : (ci == 0 ? wi : wr);
    Wcat[i] = f2bf(val);
    return;
  }
  __shared__ float xs[64][65];
  const int b   = z;
  const int l0  = blockIdx.x * 64;
  const int c0  = blockIdx.y * 64;
  const int lt  = tid & 63, r4 = tid >> 6;
#pragma unroll
  for (int p = 0; p < 16; ++p) {
    const int row  = p * 4 + r4;
    const int cin2 = c0 + row;
    const int comp = cin2 >> 8, cin = cin2 & 255;
    xs[row][lt] = x[((size_t)(comp * Bc + b) * CGc + cin) * Lc + l0 + lt];
  }
  __syncthreads();
#pragma unroll
  for (int p = 0; p < 16; ++p) {
    const int lr = p * 4 + r4;
    Xlk[((size_t)b * Lc + l0 + lr) * 512 + c0 + lt] = f2bf(xs[lt][lr]);
  }
}

// ---------------------------------------------------------------------------
// Phase 1 (fused) v2: complex Q/K projection + split-bf16 packing, with
// in-block 4-way cin-split (unchanged, verified round-10).
// ---------------------------------------------------------------------------
__global__ __launch_bounds__(1024, 4) void qk_projpack(const float* __restrict__ x,
                                                       const float* __restrict__ wq,
                                                       const float* __restrict__ wk,
                                                       unsigned short* __restrict__ Qcat,
                                                       unsigned short* __restrict__ K1hi,
                                                       unsigned short* __restrict__ K1lo,
                                                       unsigned short* __restrict__ K2hi,
                                                       unsigned short* __restrict__ K2lo) {
  __shared__ float ws[4 * Dc * CGc];   // 32 KB: wq_r | wq_i | wk_r | wk_i
  __shared__ float pq[4][32][17];      // 8.5 KB padded q partials
  __shared__ float pk[4][32][17];      // 8.5 KB padded k partials
  const int tid = threadIdx.x;
  const int b   = blockIdx.y;
  for (int i = tid; i < 2 * Dc * CGc; i += 1024) {
    ws[i]                 = wq[i];
    ws[2 * Dc * CGc + i]  = wk[i];
  }
  __syncthreads();
  const int cg  = tid >> 8;   // cin group 0..3
  const int sub = tid & 255;
  const int d   = sub >> 5;   // 0..7
  const int ml  = sub & 31;   // 0..31
  const int m   = blockIdx.x * 32 + ml;
  const int c0  = cg * 64;
  const float* xr = x + ((size_t)(0 * Bc + b) * CGc + c0) * Lc + m;
  const float* xi = x + ((size_t)(1 * Bc + b) * CGc + c0) * Lc + m;
  const float* wqr = ws + d * CGc + c0;
  const float* wqi = ws + (Dc + d) * CGc + c0;
  const float* wkr = ws + 2 * Dc * CGc + d * CGc + c0;
  const float* wki = ws + 2 * Dc * CGc + (Dc + d) * CGc + c0;
  float qer = 0.f, qei = 0.f, ker = 0.f, kei = 0.f;
#pragma unroll 4
  for (int cin = 0; cin < 64; ++cin) {
    const float vr = xr[(size_t)cin * Lc];
    const float vi = xi[(size_t)cin * Lc];
    const float a1 = wqr[cin], b1 = wqi[cin];
    qer = fmaf(a1, vr, qer); qer = fmaf(-b1, vi, qer);
    qei = fmaf(a1, vi, qei); qei = fmaf(b1, vr, qei);
    const float a2 = wkr[cin], b2 = wki[cin];
    ker = fmaf(a2, vr, ker); ker = fmaf(-b2, vi, ker);
    kei = fmaf(a2, vi, kei); kei = fmaf(b2, vr, kei);
  }
  pq[cg][ml][d]     = qer;
  pq[cg][ml][8 + d] = qei;
  pk[cg][ml][d]     = ker;
  pk[cg][ml][8 + d] = kei;
  __syncthreads();
  // --- pack stage (first 256 threads; sums 4 partials, then verified pack) ---
  if (tid < 256) {
    const int part = tid >> 5;       // 0..7
    const int rl   = tid & 31;       // local row
    const size_t r = (size_t)b * Lc + blockIdx.x * 32 + rl;
    if (part < 2) {
      unsigned u[8];
#pragma unroll
      for (int t = 0; t < 8; ++t) {
        const float v0 = ((pq[0][rl][2 * t] + pq[1][rl][2 * t]) + pq[2][rl][2 * t]) + pq[3][rl][2 * t];
        const float v1 = ((pq[0][rl][2 * t + 1] + pq[1][rl][2 * t + 1]) + pq[2][rl][2 * t + 1]) + pq[3][rl][2 * t + 1];
        const unsigned short h0 = f2bf(v0), h1 = f2bf(v1);
        if (part == 0) {
          u[t] = (unsigned)h0 | ((unsigned)h1 << 16);
        } else {
          const unsigned short l0 = f2bf(v0 - bf2f(h0));
          const unsigned short l1 = f2bf(v1 - bf2f(h1));
          u[t] = (unsigned)l0 | ((unsigned)l1 << 16);
        }
      }
      uint4* dst = (uint4*)(Qcat + r * 32 + part * 16);
      dst[0] = make_uint4(u[0], u[1], u[2], u[3]);
      dst[1] = make_uint4(u[4], u[5], u[6], u[7]);
    } else if (part < 6) {
      float ksum[16];
#pragma unroll
      for (int e = 0; e < 16; ++e)
        ksum[e] = ((pk[0][rl][e] + pk[1][rl][e]) + pk[2][rl][e]) + pk[3][rl][e];
      float kv[16];
      if (part < 4) {
#pragma unroll
        for (int e = 0; e < 8; ++e) { kv[e] = ksum[e]; kv[8 + e] = -ksum[8 + e]; }
      } else {
#pragma unroll
        for (int e = 0; e < 8; ++e) { kv[e] = ksum[8 + e]; kv[8 + e] = ksum[e]; }
      }
      const int lo = part & 1;
      unsigned u[8];
#pragma unroll
      for (int t = 0; t < 8; ++t) {
        const unsigned short h0 = f2bf(kv[2 * t]), h1 = f2bf(kv[2 * t + 1]);
        if (!lo) {
          u[t] = (unsigned)h0 | ((unsigned)h1 << 16);
        } else {
          const unsigned short l0 = f2bf(kv[2 * t] - bf2f(h0));
          const unsigned short l1 = f2bf(kv[2 * t + 1] - bf2f(h1));
          u[t] = (unsigned)l0 | ((unsigned)l1 << 16);
        }
      }
      unsigned short* base = part < 4 ? (lo ? K1lo : K1hi) : (lo ? K2lo : K2hi);
      uint4* dst = (uint4*)(base + r * 16);
      dst[0] = make_uint4(u[0], u[1], u[2], u[3]);
      dst[1] = make_uint4(u[4], u[5], u[6], u[7]);
    }
  }
}

// ---------------------------------------------------------------------------
// Phase 2: V projection as bf16 MFMA GEMM (unchanged, verified).
// ---------------------------------------------------------------------------
__global__ __launch_bounds__(256) void v_gemm(const unsigned short* __restrict__ Wcat,
                                              const unsigned short* __restrict__ Xlk,
                                              unsigned short* __restrict__ vbf) {
  __shared__ short As[128 * 64];
  __shared__ short Bs[64 * 64];
  const int tid  = threadIdx.x;
  const int b    = blockIdx.z;
  const int cc0  = blockIdx.x * 128;
  const int l0   = blockIdx.y * 64;
  const int wid  = tid >> 6, lane = tid & 63;
  const int wcc  = (wid >> 1) * 64;
  const int wl   = (wid & 1) * 32;
  const int lrow = lane & 15, quad = lane >> 4;
  floatx4 acc[4][2] = {};
  const unsigned short* wsrc = Wcat + (size_t)cc0 * 512;
  const unsigned short* xsrc = Xlk + ((size_t)b * Lc + l0) * 512;
  int s_off[4], g_off[4];
#pragma unroll
  for (int r = 0; r < 4; ++r) {
    const int idx = r * 256 + tid;
    const int row = idx >> 3, ch = idx & 7;
    s_off[r] = row * 64 + (ch ^ (row & 7)) * 8;
    g_off[r] = row * 512 + ch * 8;
  }
  short8 ar[4], br[2];
#pragma unroll
  for (int r = 0; r < 4; ++r) ar[r] = *(const short8*)(wsrc + g_off[r]);
#pragma unroll
  for (int r = 0; r < 2; ++r) br[r] = *(const short8*)(xsrc + g_off[r]);
  for (int k0 = 0; k0 < 512; k0 += 64) {
    __syncthreads();
#pragma unroll
    for (int r = 0; r < 4; ++r) *(short8*)&As[s_off[r]] = ar[r];
#pragma unroll
    for (int r = 0; r < 2; ++r) *(short8*)&Bs[s_off[r]] = br[r];
    __syncthreads();
    if (k0 + 64 < 512) {
#pragma unroll
      for (int r = 0; r < 4; ++r) ar[r] = *(const short8*)(wsrc + g_off[r] + k0 + 64);
#pragma unroll
      for (int r = 0; r < 2; ++r) br[r] = *(const short8*)(xsrc + g_off[r] + k0 + 64);
    }
#pragma unroll
    for (int kk = 0; kk < 64; kk += 32) {
      const int cb = kk >> 3;  // 0 or 4
      short8 af[4], bf[2];
#pragma unroll
      for (int i = 0; i < 4; ++i)
        af[i] = *(const short8*)&As[(wcc + i * 16 + lrow) * 64 +
                                    ((cb + quad) ^ (lrow & 7)) * 8];
#pragma unroll
      for (int j = 0; j < 2; ++j)
        bf[j] = *(const short8*)&Bs[(wl + j * 16 + lrow) * 64 +
                                    ((cb + quad) ^ (lrow & 7)) * 8];
#pragma unroll
      for (int i = 0; i < 4; ++i)
#pragma unroll
        for (int j = 0; j < 2; ++j)
          acc[i][j] = __builtin_amdgcn_mfma_f32_16x16x32_bf16(af[i], bf[j], acc[i][j], 0, 0, 0);
    }
  }
#pragma unroll
  for (int i = 0; i < 4; ++i) {
    const int ccb = cc0 + wcc + i * 16 + quad * 4;
#pragma unroll
    for (int j = 0; j < 2; ++j) {
      const int l = l0 + wl + j * 16 + lrow;
#pragma unroll
      for (int rg = 0; rg < 4; ++rg)
        vbf[((size_t)b * 512 + ccb + rg) * Lc + l] = f2bf(acc[i][j][rg]);
    }
  }
}

// ---------------------------------------------------------------------------
// Phase 3+4 fused: emax_exp v3 (unchanged, verified round-9/10): 512 blocks
// x 1024 threads, 8 waves/SIMD, 2x unroll, LDS max/sum combine.
// ---------------------------------------------------------------------------
__global__ __launch_bounds__(1024, 8) void emax_exp(const unsigned short* __restrict__ Qcat,
                                                    const unsigned short* __restrict__ K1hi,
                                                    const unsigned short* __restrict__ K1lo,
                                                    const unsigned short* __restrict__ K2hi,
                                                    const unsigned short* __restrict__ K2lo,
                                                    unsigned short* __restrict__ att,
                                                    float* __restrict__ Ssum) {
  __shared__ unsigned maxb[16];
  __shared__ float    sumb[16];
  const int tid  = threadIdx.x;
  const int wid  = tid >> 6, lane = tid & 63;
  const int lrow = lane & 15, quad = lane >> 4, qsel = quad & 1;
  const int b    = blockIdx.y;
  const int m16  = blockIdx.x * 16;   // 16 rows per block
  const int lbeg = wid * 256;         // 256-l slice per wave
  const size_t kb = (size_t)b * Lc;
  if (tid < 16) { maxb[tid] = 0u; sumb[tid] = 0.f; }
  __syncthreads();
  const short8 afrag = *(const short8*)(Qcat + (kb + m16 + lrow) * 32 + quad * 8);
  // ---- pass 1: hi-only row max, 2x unrolled (4 loads in flight) ----
  float mx[4] = {0.f, 0.f, 0.f, 0.f};
  for (int l0 = lbeg; l0 < lbeg + 256; l0 += 32) {
    short8 b1h[2], b2h[2];
#pragma unroll
    for (int u = 0; u < 2; ++u) {
      const size_t l = kb + l0 + u * 16 + lrow;
      b1h[u] = *(const short8*)(K1hi + l * 16 + qsel * 8);
      b2h[u] = *(const short8*)(K2hi + l * 16 + qsel * 8);
    }
#pragma unroll
    for (int u = 0; u < 2; ++u) {
      const floatx4 er = __builtin_amdgcn_mfma_f32_16x16x32_bf16(afrag, b1h[u], (floatx4){0.f, 0.f, 0.f, 0.f}, 0, 0, 0);
      const floatx4 ei = __builtin_amdgcn_mfma_f32_16x16x32_bf16(afrag, b2h[u], (floatx4){0.f, 0.f, 0.f, 0.f}, 0, 0, 0);
#pragma unroll
      for (int r = 0; r < 4; ++r) {
        float e = er[r] * er[r];
        e = fmaf(ei[r], ei[r], e);
        mx[r] = fmaxf(mx[r], e);
      }
    }
  }
#pragma unroll
  for (int r = 0; r < 4; ++r) {
    float v = mx[r];
#pragma unroll
    for (int off = 1; off < 16; off <<= 1) v = fmaxf(v, __shfl_xor(v, off));
    if (lrow == 0)
      atomicMax(&maxb[quad * 4 + r], __float_as_uint(v));  // E >= 0
  }
  __syncthreads();
  float Mv[4], sum[4] = {};
#pragma unroll
  for (int r = 0; r < 4; ++r) Mv[r] = __uint_as_float(maxb[quad * 4 + r]);
  // ---- pass 2: refined E, exp, att store, 2x unrolled (8 loads in flight) ----
  for (int l0 = lbeg; l0 < lbeg + 256; l0 += 32) {
    short8 b1h[2], b1l[2], b2h[2], b2l[2];
#pragma unroll
    for (int u = 0; u < 2; ++u) {
      const size_t l = kb + l0 + u * 16 + lrow;
      b1h[u] = *(const short8*)(K1hi + l * 16 + qsel * 8);
      b1l[u] = *(const short8*)(K1lo + l * 16 + qsel * 8);
      b2h[u] = *(const short8*)(K2hi + l * 16 + qsel * 8);
      b2l[u] = *(const short8*)(K2lo + l * 16 + qsel * 8);
    }
#pragma unroll
    for (int u = 0; u < 2; ++u) {
      floatx4 er = __builtin_amdgcn_mfma_f32_16x16x32_bf16(afrag, b1l[u], (floatx4){0.f, 0.f, 0.f, 0.f}, 0, 0, 0);
      er = __builtin_amdgcn_mfma_f32_16x16x32_bf16(afrag, b1h[u], er, 0, 0, 0);
      floatx4 ei = __builtin_amdgcn_mfma_f32_16x16x32_bf16(afrag, b2l[u], (floatx4){0.f, 0.f, 0.f, 0.f}, 0, 0, 0);
      ei = __builtin_amdgcn_mfma_f32_16x16x32_bf16(afrag, b2h[u], ei, 0, 0, 0);
#pragma unroll
      for (int r = 0; r < 4; ++r) {
        float e = er[r] * er[r];
        e = fmaf(ei[r], ei[r], e);
        const float wgt = __expf(e - Mv[r]);
        sum[r] += wgt;
        att[(kb + m16 + quad * 4 + r) * Lc + l0 + u * 16 + lrow] = f2bf(wgt);
      }
    }
  }
#pragma unroll
  for (int r = 0; r < 4; ++r) {
    float v = sum[r];
#pragma unroll
    for (int off = 1; off < 16; off <<= 1) v += __shfl_xor(v, off);
    if (lrow == 0) atomicAdd(&sumb[quad * 4 + r], v);
  }
  __syncthreads();
  if (tid < 16) Ssum[kb + m16 + tid] = sumb[tid];
}

// ---------------------------------------------------------------------------
// Phase 5: PV GEMM v3.2 — main loop structure unchanged (verified r7-r10);
// two schedule tweaks:
//   * removed the sched_barrier between DMA-issue and compute -> compiler
//     may interleave the 4 global_load_lds issues with ds_reads/MFMAs
//     (the sched_barrier directly after s_barrier stays: pins ds_reads
//     below the barrier, rule-18 safety).
//   * T5: s_setprio(1) around the 16-MFMA cluster (phase now has wave
//     role-diversity: DMA-issuing vs MFMA-entering waves).
// Split-K reduction lane-contiguous (r10). Same math everywhere.
// ---------------------------------------------------------------------------
__device__ __forceinline__ void pv_stage128(const unsigned short* __restrict__ vsrc,
                                            const unsigned short* __restrict__ asrc,
                                            short* lds_buf, int k0, int wid, int lane) {
  const int rsub = lane >> 4;          // 0..3: row within 4-row block
  const int cs   = lane & 15;          // LDS chunk position within 256B row
#pragma unroll
  for (int t = 0; t < 4; ++t) {
    const int q    = wid * 4 + t;      // block id 0..63 (1 KB each)
    const int tile = q >> 5;           // 0 = A(v), 1 = B(att)
    const int j    = q & 31;           // 4-row group within tile
    const int row  = j * 4 + rsub;
    const int gch  = cs ^ (row & 7);   // inverse-swizzled global k-chunk
    const unsigned short* g =
        (tile == 0 ? vsrc : asrc) + (size_t)row * Lc + k0 + gch * 8;
    short* l = lds_buf + tile * 16384 + j * 512;  // wave-uniform dest base
    __builtin_amdgcn_global_load_lds(
        (const __attribute__((address_space(1))) void*)g,
        (__attribute__((address_space(3))) void*)l, 16, 0, 0);
  }
}

__device__ __forceinline__ void pv_compute128(const short* __restrict__ As,
                                              const short* __restrict__ Bs,
                                              int cb, int wcc, int wm, int lrow, int quad,
                                              floatx4 (&acc)[4][4]) {
  short8 af[4], bf[4];
#pragma unroll
  for (int i = 0; i < 4; ++i)
    af[i] = *(const short8*)&As[(wcc + i * 16 + lrow) * 128 +
                                ((cb + quad) ^ (lrow & 7)) * 8];
#pragma unroll
  for (int j = 0; j < 4; ++j)
    bf[j] = *(const short8*)&Bs[(wm + j * 16 + lrow) * 128 +
                                ((cb + quad) ^ (lrow & 7)) * 8];
  __builtin_amdgcn_s_setprio(1);
#pragma unroll
  for (int i = 0; i < 4; ++i)
#pragma unroll
    for (int j = 0; j < 4; ++j)
      acc[i][j] = __builtin_amdgcn_mfma_f32_16x16x32_bf16(af[i], bf[j], acc[i][j], 0, 0, 0);
  __builtin_amdgcn_s_setprio(0);
}

__global__ __launch_bounds__(1024, 1) void pv_gemm(const unsigned short* __restrict__ v,
                                                   const unsigned short* __restrict__ att,
                                                   const float* __restrict__ Ssum,
                                                   const float* __restrict__ x,
                                                   const float* __restrict__ gamma,
                                                   float* __restrict__ out) {
  // 128 KB dynamic: 2 buffers x {A 128x128 | B 128x128} bf16, XOR-swizzled.
  extern __shared__ short smem[];
  // XCD-aware bijective swizzle: 256 blocks, XCD k gets contiguous work ids.
  const int flat = blockIdx.x;
  const int swz  = (flat & 7) * 32 + (flat >> 3);
  const int b    = swz >> 7;
  const int rem  = swz & 127;
  const int m0   = (rem >> 2) * 128;   // 32 m-panels
  const int cc0  = (rem & 3) * 128;    // 4 cc-panels
  const int tid  = threadIdx.x;
  const int wid  = tid >> 6, lane = tid & 63;
  const int g    = wid >> 2;           // split-K group 0..3
  const int w4   = wid & 3;
  const int wcc  = (w4 >> 1) * 64;
  const int wm   = (w4 & 1) * 64;
  const int lrow = lane & 15, quad = lane >> 4;
  const int cb   = g * 4;              // k-chunk base (of 16 chunks)
  floatx4 acc[4][4] = {};
  const unsigned short* vsrc = v   + ((size_t)b * 512 + cc0) * Lc;
  const unsigned short* asrc = att + ((size_t)b * Lc + m0) * Lc;
  // Prologue: DMA tile 0 into buf0.
  pv_stage128(vsrc, asrc, smem, 0, wid, lane);
  for (int p = 0; p < 32; ++p) {
    asm volatile("s_waitcnt vmcnt(0)" ::: "memory");
    __builtin_amdgcn_s_barrier();       // tile p complete; p-1 compute done
    __builtin_amdgcn_sched_barrier(0);  // pin ds_reads below the barrier
    if (p + 1 < 32)
      pv_stage128(vsrc, asrc, smem + ((p + 1) & 1) * 32768, (p + 1) * 128, wid, lane);
    pv_compute128(smem + (p & 1) * 32768, smem + (p & 1) * 32768 + 16384,
                  cb, wcc, wm, lrow, quad, acc);
    __builtin_amdgcn_sched_barrier(0);
  }
  __syncthreads();  // all computes done before smem reuse for reduction
  float* red = (float*)smem;  // 32768 floats = 128 KB
  // Round 1: g1 -> red[0..16383], g3 -> red[16384..32767] (lane-contiguous)
  if (g == 1 || g == 3) {
    float* dst = red + (g == 3 ? 16384 : 0);
#pragma unroll
    for (int i = 0; i < 4; ++i)
#pragma unroll
      for (int j = 0; j < 4; ++j) {
        const int tq = i * 4 + j;
        *(floatx4*)&dst[(tq * 256 + w4 * 64 + lane) * 4] = acc[i][j];
      }
  }
  __syncthreads();
  if (g == 0 || g == 2) {
    const float* src = red + (g == 2 ? 16384 : 0);
#pragma unroll
    for (int i = 0; i < 4; ++i)
#pragma unroll
      for (int j = 0; j < 4; ++j) {
        const int tq = i * 4 + j;
        const floatx4 o = *(const floatx4*)&src[(tq * 256 + w4 * 64 + lane) * 4];
        acc[i][j] += o;
      }
  }
  __syncthreads();
  // Round 2: g2 -> red[0..16383]
  if (g == 2) {
#pragma unroll
    for (int i = 0; i < 4; ++i)
#pragma unroll
      for (int j = 0; j < 4; ++j) {
        const int tq = i * 4 + j;
        *(floatx4*)&red[(tq * 256 + w4 * 64 + lane) * 4] = acc[i][j];
      }
  }
  __syncthreads();
  if (g == 0) {
#pragma unroll
    for (int i = 0; i < 4; ++i)
#pragma unroll
      for (int j = 0; j < 4; ++j) {
        const int tq = i * 4 + j;
        const floatx4 o = *(const floatx4*)&red[(tq * 256 + w4 * 64 + lane) * 4];
        acc[i][j] += o;
      }
    const float gm = gamma[0];
    float svj[4];
#pragma unroll
    for (int j = 0; j < 4; ++j)
      svj[j] = gm / Ssum[(size_t)b * Lc + m0 + wm + j * 16 + lrow];
#pragma unroll
    for (int i = 0; i < 4; ++i) {
      const int ccb = cc0 + wcc + i * 16 + quad * 4;
#pragma unroll
      for (int j = 0; j < 4; ++j) {
        const int m = m0 + wm + j * 16 + lrow;
#pragma unroll
        for (int rg = 0; rg < 4; ++rg) {
          const int cc   = ccb + rg;
          const int comp = cc >> 8, c = cc & 255;
          const size_t idx = (((size_t)comp * Bc + b) * CGc + c) * Lc + m;
          out[idx] = svj[j] * acc[i][j][rg] + x[idx];
        }
      }
    }
  }
}

// ---------------------------------------------------------------------------
extern "C" void kernel_launch(void* const* d_in, const int* in_sizes, int n_in,
                              void* d_out, int out_size, void* d_ws, size_t ws_size,
                              hipStream_t stream) {
  const float* x     = (const float*)d_in[0];
  const float* wq    = (const float*)d_in[1];
  const float* wk    = (const float*)d_in[2];
  const float* wv    = (const float*)d_in[3];
  const float* gamma = (const float*)d_in[4];
  float* out = (float*)d_out;

  // Workspace (~78.7 MB). Xlk aliases att (stream-ordered: v_gemm reads Xlk
  // before emax_exp overwrites the region with att). q/kk/Mrow slots
  // retained for layout stability (unused). Ssum needs no init (direct
  // store from emax_exp).
  float* q    = (float*)d_ws;                         // 131072 (unused)
  float* kk   = q    + (size_t)Bc * Lc * 16;          // 131072 (unused)
  float* Mrow = kk   + (size_t)Bc * Lc * 16;          // 8192 (unused)
  float* Ssum = Mrow + (size_t)Bc * Lc;               // 8192
  unsigned short* vbf  = (unsigned short*)(Ssum + (size_t)Bc * Lc);  // 2*512*4096
  unsigned short* att  = vbf + (size_t)Bc * 512 * Lc;                // 2*4096*4096
  unsigned short* Xlk  = att;                                        // alias (8.4MB)
  unsigned short* Qcat = att + (size_t)Bc * Lc * Lc;                 // 8192*32
  unsigned short* K1hi = Qcat + (size_t)Bc * Lc * 32;                // 8192*16
  unsigned short* K1lo = K1hi + (size_t)Bc * Lc * 16;
  unsigned short* K2hi = K1lo + (size_t)Bc * Lc * 16;
  unsigned short* K2lo = K2hi + (size_t)Bc * Lc * 16;
  unsigned short* Wcat = K2lo + (size_t)Bc * Lc * 16;                // 512*512

  prep_pack<<<dim3(64, 8, 4), 256, 0, stream>>>(x, wv, Xlk, Wcat);
  qk_projpack<<<dim3(Lc / 32, Bc), 1024, 0, stream>>>(x, wq, wk, Qcat, K1hi, K1lo, K2hi, K2lo);
  v_gemm<<<dim3(512 / 128, Lc / 64, Bc), 256, 0, stream>>>(Wcat, Xlk, vbf);
  emax_exp<<<dim3(Lc / 16, Bc), 1024, 0, stream>>>(Qcat, K1hi, K1lo, K2hi, K2lo, att, Ssum);
  pv_gemm<<<dim3(256), 1024, 2 * 32768 * sizeof(short), stream>>>(vbf, att, Ssum, x, gamma, out);
}